// Round 1
// baseline (1437.863 us; speedup 1.0000x reference)
//
#include <hip/hip_runtime.h>
#include <hip/hip_bf16.h>

// BCM plasticity: output = x @ W^T ; thr' = thr + (mean_b(output)^2 - thr)/TAU ;
// post = relu(output - thr') ; W' = W + (LR/B) post^T @ x
// Shapes fixed: B=8192, IN=OUT=4096, all fp32.
//
// GEMM1 in bf16x3 split precision (err ~2^-16), GEMM2 plain bf16 (delta ~1e-3 of W).
// m97-style 128x128 tile, BK=64, global_load_lds(16B), source-side XOR swizzle.

typedef __attribute__((ext_vector_type(8))) short   bf16x8;
typedef __attribute__((ext_vector_type(4))) float   f32x4;

#define ASG __attribute__((address_space(1)))
#define ASL __attribute__((address_space(3)))

__device__ __forceinline__ void gload16(const void* g, void* l) {
    __builtin_amdgcn_global_load_lds((const ASG void*)g, (ASL void*)l, 16, 0, 0);
}

// bf16 round-to-nearest-even (manual; data has no NaN/Inf)
__device__ __forceinline__ unsigned short f2bf(float x) {
    union { float f; unsigned u; } v; v.f = x;
    unsigned r = v.u;
    r += 0x7fffu + ((r >> 16) & 1u);
    return (unsigned short)(r >> 16);
}
__device__ __forceinline__ float bf2f(unsigned short u) {
    union { unsigned u; float f; } v; v.u = ((unsigned)u) << 16;
    return v.f;
}

// ---------------- conversion: f32 -> (hi, lo) bf16 ----------------
__global__ __launch_bounds__(256) void k_cvt_split(const float* __restrict__ src,
                                                   unsigned short* __restrict__ hi,
                                                   unsigned short* __restrict__ lo,
                                                   int n4) {
    int i = blockIdx.x * blockDim.x + threadIdx.x;
    int stride = gridDim.x * blockDim.x;
    for (; i < n4; i += stride) {
        float4 v = reinterpret_cast<const float4*>(src)[i];
        ushort4 h, l;
        h.x = f2bf(v.x); l.x = f2bf(v.x - bf2f(h.x));
        h.y = f2bf(v.y); l.y = f2bf(v.y - bf2f(h.y));
        h.z = f2bf(v.z); l.z = f2bf(v.z - bf2f(h.z));
        h.w = f2bf(v.w); l.w = f2bf(v.w - bf2f(h.w));
        reinterpret_cast<ushort4*>(hi)[i] = h;
        reinterpret_cast<ushort4*>(lo)[i] = l;
    }
}

// ---------------- GEMM1: C[b][o] = sum_k x[b][k]*w[o][k], bf16x3 ----------------
// A (x): [8192][4096], B (w): [4096][4096], both row-major K-contiguous.
__global__ __launch_bounds__(256) void k_gemm1(const unsigned short* __restrict__ Ah,
                                               const unsigned short* __restrict__ Al,
                                               const unsigned short* __restrict__ Bh,
                                               const unsigned short* __restrict__ Bl,
                                               float* __restrict__ C) {
    const int K = 4096, N = 4096;
    __shared__ unsigned short lAh[128 * 64], lAl[128 * 64], lBh[128 * 64], lBl[128 * 64];

    const int t    = threadIdx.x;
    const int lane = t & 63, wid = t >> 6;
    const int ln15 = lane & 15, l16 = lane >> 4;
    const int wm   = wid >> 1, wn = wid & 1;
    const int bm   = blockIdx.y, bn = blockIdx.x;

    // staging: wave-group g covers rows g*8..g*8+7 (128B rows, 8 chunks of 16B)
    // LDS linear (row, chunkL=lane&7) holds global chunk (chunkL ^ (row&7))
    const int srow   = lane >> 3;                       // 0..7
    const int schunk = (lane & 7) ^ (srow & 7);
    const size_t aBase = (size_t)(bm * 128 + wid * 8 + srow) * K + schunk * 8;
    const size_t bBase = (size_t)(bn * 128 + wid * 8 + srow) * K + schunk * 8;

    f32x4 acc[4][4];
#pragma unroll
    for (int i = 0; i < 4; ++i)
#pragma unroll
        for (int j = 0; j < 4; ++j) acc[i][j] = (f32x4){0.f, 0.f, 0.f, 0.f};

    for (int k0 = 0; k0 < K; k0 += 64) {
        __syncthreads();
#pragma unroll
        for (int i = 0; i < 4; ++i) {
            const int g = i * 4 + wid;
            const size_t ro = (size_t)i * 32 * K;
            const int lo_ = g * 512 + lane * 8;  // ushort index; lane*16B linear
            gload16(Ah + aBase + ro + k0, &lAh[lo_]);
            gload16(Al + aBase + ro + k0, &lAl[lo_]);
            gload16(Bh + bBase + ro + k0, &lBh[lo_]);
            gload16(Bl + bBase + ro + k0, &lBl[lo_]);
        }
        __syncthreads();

#pragma unroll
        for (int kk = 0; kk < 2; ++kk) {
            bf16x8 ah[4], al[4], bh[4], bl[4];
#pragma unroll
            for (int mi = 0; mi < 4; ++mi) {
                const int r   = wm * 64 + mi * 16 + ln15;
                const int idx = r * 64 + (((l16 + kk * 4) ^ (r & 7)) * 8);
                ah[mi] = *(const bf16x8*)&lAh[idx];
                al[mi] = *(const bf16x8*)&lAl[idx];
            }
#pragma unroll
            for (int ni = 0; ni < 4; ++ni) {
                const int r   = wn * 64 + ni * 16 + ln15;
                const int idx = r * 64 + (((l16 + kk * 4) ^ (r & 7)) * 8);
                bh[ni] = *(const bf16x8*)&lBh[idx];
                bl[ni] = *(const bf16x8*)&lBl[idx];
            }
#pragma unroll
            for (int mi = 0; mi < 4; ++mi)
#pragma unroll
                for (int ni = 0; ni < 4; ++ni) {
                    acc[mi][ni] = __builtin_amdgcn_mfma_f32_16x16x32_bf16(ah[mi], bh[ni], acc[mi][ni], 0, 0, 0);
                    acc[mi][ni] = __builtin_amdgcn_mfma_f32_16x16x32_bf16(ah[mi], bl[ni], acc[mi][ni], 0, 0, 0);
                    acc[mi][ni] = __builtin_amdgcn_mfma_f32_16x16x32_bf16(al[mi], bh[ni], acc[mi][ni], 0, 0, 0);
                }
        }
    }

    const int row0 = bm * 128 + wm * 64;
    const int col0 = bn * 128 + wn * 64;
#pragma unroll
    for (int mi = 0; mi < 4; ++mi)
#pragma unroll
        for (int ni = 0; ni < 4; ++ni)
#pragma unroll
            for (int j = 0; j < 4; ++j) {
                const int row = row0 + mi * 16 + l16 * 4 + j;   // C/D: row=(lane>>4)*4+reg
                const int col = col0 + ni * 16 + ln15;          //      col=lane&15
                C[(size_t)row * N + col] = acc[mi][ni][j];
            }
}

// ---------------- GEMM2: Wout[o][i] = Wf[o][i] + scale * sum_b postT[o][b]*xT[i][b] ----------------
__global__ __launch_bounds__(256) void k_gemm2(const unsigned short* __restrict__ A,   // postT [4096][8192]
                                               const unsigned short* __restrict__ Bx,  // xT    [4096][8192]
                                               const float* __restrict__ Wf,
                                               float* __restrict__ Wout, float scale) {
    const int K = 8192, N = 4096;
    __shared__ unsigned short lA[128 * 64], lB[128 * 64];

    const int t    = threadIdx.x;
    const int lane = t & 63, wid = t >> 6;
    const int ln15 = lane & 15, l16 = lane >> 4;
    const int wm   = wid >> 1, wn = wid & 1;
    const int bm   = blockIdx.y, bn = blockIdx.x;

    const int srow   = lane >> 3;
    const int schunk = (lane & 7) ^ (srow & 7);
    const size_t aBase = (size_t)(bm * 128 + wid * 8 + srow) * K + schunk * 8;
    const size_t bBase = (size_t)(bn * 128 + wid * 8 + srow) * K + schunk * 8;

    f32x4 acc[4][4];
#pragma unroll
    for (int i = 0; i < 4; ++i)
#pragma unroll
        for (int j = 0; j < 4; ++j) acc[i][j] = (f32x4){0.f, 0.f, 0.f, 0.f};

    for (int k0 = 0; k0 < K; k0 += 64) {
        __syncthreads();
#pragma unroll
        for (int i = 0; i < 4; ++i) {
            const int g = i * 4 + wid;
            const size_t ro = (size_t)i * 32 * K;
            const int lo_ = g * 512 + lane * 8;
            gload16(A + aBase + ro + k0, &lA[lo_]);
            gload16(Bx + bBase + ro + k0, &lB[lo_]);
        }
        __syncthreads();

#pragma unroll
        for (int kk = 0; kk < 2; ++kk) {
            bf16x8 a[4], b[4];
#pragma unroll
            for (int mi = 0; mi < 4; ++mi) {
                const int r   = wm * 64 + mi * 16 + ln15;
                const int idx = r * 64 + (((l16 + kk * 4) ^ (r & 7)) * 8);
                a[mi] = *(const bf16x8*)&lA[idx];
            }
#pragma unroll
            for (int ni = 0; ni < 4; ++ni) {
                const int r   = wn * 64 + ni * 16 + ln15;
                const int idx = r * 64 + (((l16 + kk * 4) ^ (r & 7)) * 8);
                b[ni] = *(const bf16x8*)&lB[idx];
            }
#pragma unroll
            for (int mi = 0; mi < 4; ++mi)
#pragma unroll
                for (int ni = 0; ni < 4; ++ni)
                    acc[mi][ni] = __builtin_amdgcn_mfma_f32_16x16x32_bf16(a[mi], b[ni], acc[mi][ni], 0, 0, 0);
        }
    }

    const int row0 = bm * 128 + wm * 64;
    const int col0 = bn * 128 + wn * 64;
#pragma unroll
    for (int mi = 0; mi < 4; ++mi)
#pragma unroll
        for (int ni = 0; ni < 4; ++ni)
#pragma unroll
            for (int j = 0; j < 4; ++j) {
                const int row = row0 + mi * 16 + l16 * 4 + j;
                const int col = col0 + ni * 16 + ln15;
                const size_t idx = (size_t)row * N + col;
                Wout[idx] = Wf[idx] + scale * acc[mi][ni][j];
            }
}

// ---------------- column sum of output (for activity) ----------------
__global__ __launch_bounds__(256) void k_colsum(const float* __restrict__ out,
                                                float* __restrict__ acc) {
    const int col = blockIdx.x * 256 + threadIdx.x;
    const int r0  = blockIdx.y * 128;
    float s = 0.f;
#pragma unroll 4
    for (int r = 0; r < 128; ++r) s += out[(size_t)(r0 + r) * 4096 + col];
    atomicAdd(&acc[col], s);
}

__global__ __launch_bounds__(256) void k_thr(const float* __restrict__ acc,
                                             const float* __restrict__ thr_in,
                                             float* __restrict__ thr_out) {
    const int o = blockIdx.x * 256 + threadIdx.x;
    const float act = acc[o] * (1.0f / 8192.0f);
    const float t0  = thr_in[o];
    thr_out[o] = t0 + (act * act - t0) / 1000.0f;
}

// ---------------- postT: relu(out - thr) transposed to [OUT][B] bf16 ----------------
__global__ __launch_bounds__(256) void k_postT(const float* __restrict__ out,
                                               const float* __restrict__ thr,
                                               unsigned short* __restrict__ postT) {
    __shared__ unsigned short tile[64][65];
    __shared__ float sthr[64];
    const int b0 = blockIdx.y * 64, o0 = blockIdx.x * 64;
    if (threadIdx.x < 64) sthr[threadIdx.x] = thr[o0 + threadIdx.x];
    __syncthreads();
#pragma unroll
    for (int it = 0; it < 16; ++it) {
        int idx = it * 256 + threadIdx.x;
        int r = idx >> 6, c = idx & 63;
        float v = out[(size_t)(b0 + r) * 4096 + o0 + c] - sthr[c];
        tile[r][c] = f2bf(v > 0.f ? v : 0.f);
    }
    __syncthreads();
#pragma unroll
    for (int it = 0; it < 16; ++it) {
        int idx = it * 256 + threadIdx.x;
        int r = idx >> 6, c = idx & 63;   // r: o-offset, c: b-offset
        postT[(size_t)(o0 + r) * 8192 + b0 + c] = tile[c][r];
    }
}

// ---------------- xT: x [B][IN] f32 -> xT [IN][B] bf16 ----------------
__global__ __launch_bounds__(256) void k_xT(const float* __restrict__ x,
                                            unsigned short* __restrict__ xT) {
    __shared__ unsigned short tile[64][65];
    const int b0 = blockIdx.y * 64, i0 = blockIdx.x * 64;
#pragma unroll
    for (int it = 0; it < 16; ++it) {
        int idx = it * 256 + threadIdx.x;
        int r = idx >> 6, c = idx & 63;
        tile[r][c] = f2bf(x[(size_t)(b0 + r) * 4096 + i0 + c]);
    }
    __syncthreads();
#pragma unroll
    for (int it = 0; it < 16; ++it) {
        int idx = it * 256 + threadIdx.x;
        int r = idx >> 6, c = idx & 63;
        xT[(size_t)(i0 + r) * 8192 + b0 + c] = tile[c][r];
    }
}

extern "C" void kernel_launch(void* const* d_in, const int* in_sizes, int n_in,
                              void* d_out, int out_size, void* d_ws, size_t ws_size,
                              hipStream_t stream) {
    const float* x   = (const float*)d_in[0];   // [8192][4096]
    const float* w   = (const float*)d_in[1];   // [4096][4096]
    const float* thr = (const float*)d_in[2];   // [4096]
    const int B = 8192, IN = 4096, OUT = 4096;

    float* out_y   = (float*)d_out;                  // [B][OUT]
    float* out_thr = out_y + (size_t)B * OUT;        // [OUT]
    float* out_w   = out_thr + OUT;                  // [OUT][IN]

    // ws layout (needs ~201.4 MB):
    //   [0,16K)       : activity accumulator (f32[4096])
    //   +64K          : x_hi  (bf16 [B][IN], 64 MiB)
    //   next          : x_lo  (64 MiB)  -- reused as postT [OUT][B] after GEMM1
    //   next          : w_hi  (32 MiB)  \__ reused as xT [IN][B] (64 MiB) after GEMM1
    //   next          : w_lo  (32 MiB)  /
    char* ws = (char*)d_ws;
    float* acc_act       = (float*)ws;
    unsigned short* x_hi = (unsigned short*)(ws + 65536);
    unsigned short* x_lo = x_hi + (size_t)B * IN;
    unsigned short* w_hi = x_lo + (size_t)B * IN;
    unsigned short* w_lo = w_hi + (size_t)OUT * IN;
    unsigned short* postT = x_lo;   // alias, safe after GEMM1
    unsigned short* xT    = w_hi;   // alias (w_hi+w_lo = 64 MiB), safe after GEMM1
    (void)w_lo; (void)ws_size;

    hipMemsetAsync(acc_act, 0, OUT * sizeof(float), stream);

    k_cvt_split<<<2048, 256, 0, stream>>>(x, x_hi, x_lo, B * IN / 4);
    k_cvt_split<<<2048, 256, 0, stream>>>(w, w_hi, w_lo, OUT * IN / 4);

    k_gemm1<<<dim3(OUT / 128, B / 128), 256, 0, stream>>>(x_hi, x_lo, w_hi, w_lo, out_y);

    k_colsum<<<dim3(OUT / 256, B / 128), 256, 0, stream>>>(out_y, acc_act);
    k_thr<<<OUT / 256, 256, 0, stream>>>(acc_act, thr, out_thr);

    k_postT<<<dim3(OUT / 64, B / 64), 256, 0, stream>>>(out_y, out_thr, postT);
    k_xT<<<dim3(IN / 64, B / 64), 256, 0, stream>>>(x, xT);

    k_gemm2<<<dim3(IN / 128, OUT / 128), 256, 0, stream>>>(postT, xT, w, out_w,
                                                           (float)(0.001 / 8192.0));
}

// Round 2
// 1386.893 us; speedup vs baseline: 1.0368x; 1.0368x over previous
//
#include <hip/hip_runtime.h>
#include <hip/hip_bf16.h>

// BCM plasticity: output = x @ W^T ; thr' = thr + (mean_b(output)^2 - thr)/TAU ;
// post = relu(output - thr') ; W' = W + (LR/B) post^T @ x
// B=8192, IN=OUT=4096, fp32.
// GEMM1 bf16x3 (ah*bh + ah*bl + al*bh), GEMM2 plain bf16.
// Ring-3 K-tile pipeline: raw s_barrier (no drain), counted vmcnt(6), setprio,
// gload_lds(16B) with source-side XOR swizzle (verified 0 bank conflicts in R1).

typedef __attribute__((ext_vector_type(8))) short   bf16x8;
typedef __attribute__((ext_vector_type(4))) float   f32x4;

#define ASG __attribute__((address_space(1)))
#define ASL __attribute__((address_space(3)))

__device__ __forceinline__ void gload16(const void* g, void* l) {
    __builtin_amdgcn_global_load_lds((const ASG void*)g, (ASL void*)l, 16, 0, 0);
}

__device__ __forceinline__ unsigned short f2bf(float x) {
    union { float f; unsigned u; } v; v.f = x;
    unsigned r = v.u;
    r += 0x7fffu + ((r >> 16) & 1u);
    return (unsigned short)(r >> 16);
}
__device__ __forceinline__ float bf2f(unsigned short u) {
    union { unsigned u; float f; } v; v.u = ((unsigned)u) << 16;
    return v.f;
}

// ---------------- conversion: f32 -> (hi, lo) bf16 ----------------
__global__ __launch_bounds__(256) void k_cvt_split(const float* __restrict__ src,
                                                   unsigned short* __restrict__ hi,
                                                   unsigned short* __restrict__ lo,
                                                   int n4) {
    int i = blockIdx.x * blockDim.x + threadIdx.x;
    int stride = gridDim.x * blockDim.x;
    for (; i < n4; i += stride) {
        float4 v = reinterpret_cast<const float4*>(src)[i];
        ushort4 h, l;
        h.x = f2bf(v.x); l.x = f2bf(v.x - bf2f(h.x));
        h.y = f2bf(v.y); l.y = f2bf(v.y - bf2f(h.y));
        h.z = f2bf(v.z); l.z = f2bf(v.z - bf2f(h.z));
        h.w = f2bf(v.w); l.w = f2bf(v.w - bf2f(h.w));
        reinterpret_cast<ushort4*>(hi)[i] = h;
        reinterpret_cast<ushort4*>(lo)[i] = l;
    }
}

// ---------------- GEMM1: C[b][o] = sum_k x[b][k]*w[o][k], bf16x3 ----------------
// Tile 256(M)x128(N), BK=32, ring-3. Slot: Ah[0,8192) Al[8192,16384)
// Bh[16384,20480) Bl[20480,24576) ushorts (48 KB).
__global__ __launch_bounds__(512, 2) void k_gemm1(const unsigned short* __restrict__ Ah,
                                                  const unsigned short* __restrict__ Al,
                                                  const unsigned short* __restrict__ Bh,
                                                  const unsigned short* __restrict__ Bl,
                                                  float* __restrict__ C,
                                                  float* __restrict__ acc_act) {
    __shared__ unsigned short sm[3 * 24576];   // 144 KiB
    const int t = threadIdx.x, lane = t & 63, ln15 = lane & 15, l16 = lane >> 4;
    const int wid = t >> 6, wm = wid >> 2, wn = wid & 3;
    const int nwg = gridDim.x, bid = blockIdx.x;
    const int wg  = (bid & 7) * (nwg >> 3) + (bid >> 3);        // XCD swizzle (nwg%8==0)
    const int bm = wg >> 5, bn = wg & 31;                        // 32 x 32 blocks
    const int arow0 = bm * 256, brow0 = bn * 128;

    // staging: 6 gload_lds(16B)/thread/tile; LDS linear, source pre-swizzled
    const unsigned short* gsrc[6];
    int ldso[6];
#pragma unroll
    for (int j = 0; j < 6; ++j) {
        const int c = j * 512 + t;
        if (c < 1024)      { int cc = c;        int row = cc >> 2, chk = (cc & 3) ^ (row & 3); gsrc[j] = Ah + (size_t)(arow0 + row) * 4096 + chk * 8; ldso[j] = cc * 8; }
        else if (c < 2048) { int cc = c - 1024; int row = cc >> 2, chk = (cc & 3) ^ (row & 3); gsrc[j] = Al + (size_t)(arow0 + row) * 4096 + chk * 8; ldso[j] = 8192 + cc * 8; }
        else if (c < 2560) { int cc = c - 2048; int row = cc >> 2, chk = (cc & 3) ^ (row & 3); gsrc[j] = Bh + (size_t)(brow0 + row) * 4096 + chk * 8; ldso[j] = 16384 + cc * 8; }
        else               { int cc = c - 2560; int row = cc >> 2, chk = (cc & 3) ^ (row & 3); gsrc[j] = Bl + (size_t)(brow0 + row) * 4096 + chk * 8; ldso[j] = 20480 + cc * 8; }
    }

    // fragment LDS offsets (read-side swizzle = staging swizzle)
    int aoh[8], aol[8], boh[2], bol[2];
#pragma unroll
    for (int mi = 0; mi < 8; ++mi) {
        const int r = wm * 128 + mi * 16 + ln15;
        const int sw = (l16 ^ (r & 3)) * 8;
        aoh[mi] = r * 32 + sw; aol[mi] = 8192 + r * 32 + sw;
    }
#pragma unroll
    for (int ni = 0; ni < 2; ++ni) {
        const int r = wn * 32 + ni * 16 + ln15;
        const int sw = (l16 ^ (r & 3)) * 8;
        boh[ni] = 16384 + r * 32 + sw; bol[ni] = 20480 + r * 32 + sw;
    }

    f32x4 acc[8][2];
#pragma unroll
    for (int mi = 0; mi < 8; ++mi)
#pragma unroll
        for (int ni = 0; ni < 2; ++ni) acc[mi][ni] = (f32x4){0.f, 0.f, 0.f, 0.f};

    // prologue: stage tiles 0,1 into slots 0,1 (12 loads in flight)
#pragma unroll
    for (int j = 0; j < 6; ++j) gload16(gsrc[j], sm + ldso[j]);
#pragma unroll
    for (int j = 0; j < 6; ++j) gload16(gsrc[j] + 32, sm + 24576 + ldso[j]);

    int scur = 0, snxt = 2;
    for (int kt = 0; kt < 128; ++kt) {
        asm volatile("s_waitcnt vmcnt(6)" ::: "memory");   // tile kt's 6 loads landed
        __builtin_amdgcn_s_barrier();                      // all waves' loads in; kt-1 reads done
        asm volatile("" ::: "memory");
        const unsigned short* rb = sm + scur * 24576;
        bf16x8 vah[8], val[8], vbh[2], vbl[2];
#pragma unroll
        for (int mi = 0; mi < 8; ++mi) { vah[mi] = *(const bf16x8*)(rb + aoh[mi]); val[mi] = *(const bf16x8*)(rb + aol[mi]); }
#pragma unroll
        for (int ni = 0; ni < 2; ++ni) { vbh[ni] = *(const bf16x8*)(rb + boh[ni]); vbl[ni] = *(const bf16x8*)(rb + bol[ni]); }
        { // stage tile kt+2 into slot snxt (= slot of kt-1, freed by barrier above)
            const size_t ko = (size_t)((kt + 2 < 128) ? kt + 2 : 127) * 32;
            unsigned short* sb = sm + snxt * 24576;
#pragma unroll
            for (int j = 0; j < 6; ++j) gload16(gsrc[j] + ko, sb + ldso[j]);
        }
        __builtin_amdgcn_s_setprio(1);
#pragma unroll
        for (int mi = 0; mi < 8; ++mi)
#pragma unroll
            for (int ni = 0; ni < 2; ++ni) {
                acc[mi][ni] = __builtin_amdgcn_mfma_f32_16x16x32_bf16(vah[mi], vbh[ni], acc[mi][ni], 0, 0, 0);
                acc[mi][ni] = __builtin_amdgcn_mfma_f32_16x16x32_bf16(vah[mi], vbl[ni], acc[mi][ni], 0, 0, 0);
                acc[mi][ni] = __builtin_amdgcn_mfma_f32_16x16x32_bf16(val[mi], vbh[ni], acc[mi][ni], 0, 0, 0);
            }
        __builtin_amdgcn_s_setprio(0);
        scur = (scur == 2) ? 0 : scur + 1;
        snxt = (snxt == 2) ? 0 : snxt + 1;
    }
    asm volatile("s_waitcnt vmcnt(0)" ::: "memory");       // drain before LDS dealloc

    // epilogue: C write + fused column-sum (activity)
    const int row0 = bm * 256 + wm * 128, col0 = bn * 128 + wn * 32;
    float cs0 = 0.f, cs1 = 0.f;
#pragma unroll
    for (int mi = 0; mi < 8; ++mi)
#pragma unroll
        for (int j = 0; j < 4; ++j) {
            const int row = row0 + mi * 16 + l16 * 4 + j;
            C[(size_t)row * 4096 + col0 + ln15]      = acc[mi][0][j];
            C[(size_t)row * 4096 + col0 + 16 + ln15] = acc[mi][1][j];
            cs0 += acc[mi][0][j]; cs1 += acc[mi][1][j];
        }
    cs0 += __shfl_xor(cs0, 16, 64); cs0 += __shfl_xor(cs0, 32, 64);
    cs1 += __shfl_xor(cs1, 16, 64); cs1 += __shfl_xor(cs1, 32, 64);
    if (l16 == 0) {
        atomicAdd(&acc_act[col0 + ln15], cs0);
        atomicAdd(&acc_act[col0 + 16 + ln15], cs1);
    }
}

// ---------------- GEMM2: Wout[o][i] = Wf[o][i] + scale * sum_b postT[o][b]*xT[i][b] ----------------
// Tile 256(M)x128(N), BK=64, ring-3. Slot: A[0,16384) B[16384,24576) ushorts.
__global__ __launch_bounds__(512, 2) void k_gemm2(const unsigned short* __restrict__ A,
                                                  const unsigned short* __restrict__ Bx,
                                                  const float* __restrict__ Wf,
                                                  float* __restrict__ Wout, float scale) {
    __shared__ unsigned short sm[3 * 24576];   // 144 KiB
    const int t = threadIdx.x, lane = t & 63, ln15 = lane & 15, l16 = lane >> 4;
    const int wid = t >> 6, wm = wid >> 2, wn = wid & 3;
    const int nwg = gridDim.x, bid = blockIdx.x;
    const int wg  = (bid & 7) * (nwg >> 3) + (bid >> 3);
    const int bm = wg >> 5, bn = wg & 31;                       // 16 x 32 blocks
    const int arow0 = bm * 256, brow0 = bn * 128;

    const unsigned short* gsrc[6];
    int ldso[6];
#pragma unroll
    for (int j = 0; j < 6; ++j) {
        const int c = j * 512 + t;
        if (c < 2048) { int row = c >> 3, chk = (c & 7) ^ (row & 7); gsrc[j] = A + (size_t)(arow0 + row) * 8192 + chk * 8; ldso[j] = c * 8; }
        else { int cc = c - 2048; int row = cc >> 3, chk = (cc & 7) ^ (row & 7); gsrc[j] = Bx + (size_t)(brow0 + row) * 8192 + chk * 8; ldso[j] = 16384 + cc * 8; }
    }

    int ao0[8], ao1[8], bo0[2], bo1[2];
#pragma unroll
    for (int mi = 0; mi < 8; ++mi) {
        const int r = wm * 128 + mi * 16 + ln15;
        ao0[mi] = r * 64 + ((l16 ^ (r & 7)) * 8);
        ao1[mi] = r * 64 + (((4 + l16) ^ (r & 7)) * 8);
    }
#pragma unroll
    for (int ni = 0; ni < 2; ++ni) {
        const int r = wn * 32 + ni * 16 + ln15;
        bo0[ni] = 16384 + r * 64 + ((l16 ^ (r & 7)) * 8);
        bo1[ni] = 16384 + r * 64 + (((4 + l16) ^ (r & 7)) * 8);
    }

    f32x4 acc[8][2];
#pragma unroll
    for (int mi = 0; mi < 8; ++mi)
#pragma unroll
        for (int ni = 0; ni < 2; ++ni) acc[mi][ni] = (f32x4){0.f, 0.f, 0.f, 0.f};

#pragma unroll
    for (int j = 0; j < 6; ++j) gload16(gsrc[j], sm + ldso[j]);
#pragma unroll
    for (int j = 0; j < 6; ++j) gload16(gsrc[j] + 64, sm + 24576 + ldso[j]);

    int scur = 0, snxt = 2;
    for (int kt = 0; kt < 128; ++kt) {
        asm volatile("s_waitcnt vmcnt(6)" ::: "memory");
        __builtin_amdgcn_s_barrier();
        asm volatile("" ::: "memory");
        const unsigned short* rb = sm + scur * 24576;
        bf16x8 va[8], vb[2];
#pragma unroll
        for (int mi = 0; mi < 8; ++mi) va[mi] = *(const bf16x8*)(rb + ao0[mi]);
#pragma unroll
        for (int ni = 0; ni < 2; ++ni) vb[ni] = *(const bf16x8*)(rb + bo0[ni]);
        { const size_t ko = (size_t)((kt + 2 < 128) ? kt + 2 : 127) * 64;
          unsigned short* sb = sm + snxt * 24576;
#pragma unroll
          for (int j = 0; j < 6; ++j) gload16(gsrc[j] + ko, sb + ldso[j]);
        }
        __builtin_amdgcn_s_setprio(1);
#pragma unroll
        for (int mi = 0; mi < 8; ++mi)
#pragma unroll
            for (int ni = 0; ni < 2; ++ni)
                acc[mi][ni] = __builtin_amdgcn_mfma_f32_16x16x32_bf16(va[mi], vb[ni], acc[mi][ni], 0, 0, 0);
        __builtin_amdgcn_s_setprio(0);
        // kk = 1
#pragma unroll
        for (int mi = 0; mi < 8; ++mi) va[mi] = *(const bf16x8*)(rb + ao1[mi]);
#pragma unroll
        for (int ni = 0; ni < 2; ++ni) vb[ni] = *(const bf16x8*)(rb + bo1[ni]);
        __builtin_amdgcn_s_setprio(1);
#pragma unroll
        for (int mi = 0; mi < 8; ++mi)
#pragma unroll
            for (int ni = 0; ni < 2; ++ni)
                acc[mi][ni] = __builtin_amdgcn_mfma_f32_16x16x32_bf16(va[mi], vb[ni], acc[mi][ni], 0, 0, 0);
        __builtin_amdgcn_s_setprio(0);
        scur = (scur == 2) ? 0 : scur + 1;
        snxt = (snxt == 2) ? 0 : snxt + 1;
    }
    asm volatile("s_waitcnt vmcnt(0)" ::: "memory");

    const int row0 = bm * 256 + wm * 128, col0 = bn * 128 + wn * 32;
#pragma unroll
    for (int mi = 0; mi < 8; ++mi)
#pragma unroll
        for (int j = 0; j < 4; ++j) {
            const int row = row0 + mi * 16 + l16 * 4 + j;
            const size_t i0 = (size_t)row * 4096 + col0 + ln15;
            const size_t i1 = i0 + 16;
            Wout[i0] = Wf[i0] + scale * acc[mi][0][j];
            Wout[i1] = Wf[i1] + scale * acc[mi][1][j];
        }
}

// ---------------- threshold EMA ----------------
__global__ __launch_bounds__(256) void k_thr(const float* __restrict__ acc,
                                             const float* __restrict__ thr_in,
                                             float* __restrict__ thr_out) {
    const int o = blockIdx.x * 256 + threadIdx.x;
    const float act = acc[o] * (1.0f / 8192.0f);
    const float t0  = thr_in[o];
    thr_out[o] = t0 + (act * act - t0) / 1000.0f;
}

// ---------------- postT: relu(out - thr) transposed to [OUT][B] bf16 ----------------
__global__ __launch_bounds__(256) void k_postT(const float* __restrict__ out,
                                               const float* __restrict__ thr,
                                               unsigned short* __restrict__ postT) {
    __shared__ unsigned short tile[64][65];
    __shared__ float sthr[64];
    const int b0 = blockIdx.y * 64, o0 = blockIdx.x * 64;
    if (threadIdx.x < 64) sthr[threadIdx.x] = thr[o0 + threadIdx.x];
    __syncthreads();
#pragma unroll
    for (int it = 0; it < 16; ++it) {
        int idx = it * 256 + threadIdx.x;
        int r = idx >> 6, c = idx & 63;
        float v = out[(size_t)(b0 + r) * 4096 + o0 + c] - sthr[c];
        tile[r][c] = f2bf(v > 0.f ? v : 0.f);
    }
    __syncthreads();
#pragma unroll
    for (int it = 0; it < 16; ++it) {
        int idx = it * 256 + threadIdx.x;
        int r = idx >> 6, c = idx & 63;
        postT[(size_t)(o0 + r) * 8192 + b0 + c] = tile[c][r];
    }
}

// ---------------- xT: x [B][IN] f32 -> xT [IN][B] bf16 ----------------
__global__ __launch_bounds__(256) void k_xT(const float* __restrict__ x,
                                            unsigned short* __restrict__ xT) {
    __shared__ unsigned short tile[64][65];
    const int b0 = blockIdx.y * 64, i0 = blockIdx.x * 64;
#pragma unroll
    for (int it = 0; it < 16; ++it) {
        int idx = it * 256 + threadIdx.x;
        int r = idx >> 6, c = idx & 63;
        tile[r][c] = f2bf(x[(size_t)(b0 + r) * 4096 + i0 + c]);
    }
    __syncthreads();
#pragma unroll
    for (int it = 0; it < 16; ++it) {
        int idx = it * 256 + threadIdx.x;
        int r = idx >> 6, c = idx & 63;
        xT[(size_t)(i0 + r) * 8192 + b0 + c] = tile[c][r];
    }
}

extern "C" void kernel_launch(void* const* d_in, const int* in_sizes, int n_in,
                              void* d_out, int out_size, void* d_ws, size_t ws_size,
                              hipStream_t stream) {
    const float* x   = (const float*)d_in[0];   // [8192][4096]
    const float* w   = (const float*)d_in[1];   // [4096][4096]
    const float* thr = (const float*)d_in[2];   // [4096]
    const int B = 8192, IN = 4096, OUT = 4096;

    float* out_y   = (float*)d_out;                  // [B][OUT]
    float* out_thr = out_y + (size_t)B * OUT;        // [OUT]
    float* out_w   = out_thr + OUT;                  // [OUT][IN]

    char* ws = (char*)d_ws;
    float* acc_act       = (float*)ws;
    unsigned short* x_hi = (unsigned short*)(ws + 65536);
    unsigned short* x_lo = x_hi + (size_t)B * IN;
    unsigned short* w_hi = x_lo + (size_t)B * IN;
    unsigned short* w_lo = w_hi + (size_t)OUT * IN;
    unsigned short* postT = x_lo;   // alias, safe after GEMM1
    unsigned short* xT    = w_hi;   // alias (w_hi+w_lo span), safe after GEMM1
    (void)w_lo; (void)ws_size;

    hipMemsetAsync(acc_act, 0, OUT * sizeof(float), stream);

    k_cvt_split<<<2048, 256, 0, stream>>>(x, x_hi, x_lo, B * IN / 4);
    k_cvt_split<<<2048, 256, 0, stream>>>(w, w_hi, w_lo, OUT * IN / 4);

    k_gemm1<<<1024, 512, 0, stream>>>(x_hi, x_lo, w_hi, w_lo, out_y, acc_act);

    k_thr<<<OUT / 256, 256, 0, stream>>>(acc_act, thr, out_thr);

    k_postT<<<dim3(OUT / 64, B / 64), 256, 0, stream>>>(out_y, out_thr, postT);
    k_xT<<<dim3(IN / 64, B / 64), 256, 0, stream>>>(x, xT);

    k_gemm2<<<512, 512, 0, stream>>>(postT, xT, w, out_w, (float)(0.001 / 8192.0));
}

// Round 3
// 1375.276 us; speedup vs baseline: 1.0455x; 1.0084x over previous
//
#include <hip/hip_runtime.h>
#include <hip/hip_bf16.h>

// BCM plasticity: output = x @ W^T ; thr' = thr + (mean_b(output)^2 - thr)/TAU ;
// post = relu(output - thr') ; W' = W + (LR/B) post^T @ x
// B=8192, IN=OUT=4096, fp32.
// GEMM1 bf16x3 (ah*bh + ah*bl + al*bh), GEMM2 plain bf16.
// Ring-3 K-tile pipeline, counted vmcnt(6), raw barriers, setprio.
// R3 fix: GEMM1 LDS XOR uses ((row>>1)&3) so bank-starts have period 8
// (R2's (row&3) collapsed to 4 starts -> 4-way conflict, 8.4e7 counted).

typedef __attribute__((ext_vector_type(8))) short   bf16x8;
typedef __attribute__((ext_vector_type(4))) float   f32x4;

#define ASG __attribute__((address_space(1)))
#define ASL __attribute__((address_space(3)))

__device__ __forceinline__ void gload16(const void* g, void* l) {
    __builtin_amdgcn_global_load_lds((const ASG void*)g, (ASL void*)l, 16, 0, 0);
}

__device__ __forceinline__ unsigned short f2bf(float x) {
    union { float f; unsigned u; } v; v.f = x;
    unsigned r = v.u;
    r += 0x7fffu + ((r >> 16) & 1u);
    return (unsigned short)(r >> 16);
}
__device__ __forceinline__ float bf2f(unsigned short u) {
    union { unsigned u; float f; } v; v.u = ((unsigned)u) << 16;
    return v.f;
}

// ---------------- conversion: f32 -> (hi, lo) bf16 (used for W) ----------------
__global__ __launch_bounds__(256) void k_cvt_split(const float* __restrict__ src,
                                                   unsigned short* __restrict__ hi,
                                                   unsigned short* __restrict__ lo,
                                                   int n4) {
    int i = blockIdx.x * blockDim.x + threadIdx.x;
    int stride = gridDim.x * blockDim.x;
    for (; i < n4; i += stride) {
        float4 v = reinterpret_cast<const float4*>(src)[i];
        ushort4 h, l;
        h.x = f2bf(v.x); l.x = f2bf(v.x - bf2f(h.x));
        h.y = f2bf(v.y); l.y = f2bf(v.y - bf2f(h.y));
        h.z = f2bf(v.z); l.z = f2bf(v.z - bf2f(h.z));
        h.w = f2bf(v.w); l.w = f2bf(v.w - bf2f(h.w));
        reinterpret_cast<ushort4*>(hi)[i] = h;
        reinterpret_cast<ushort4*>(lo)[i] = l;
    }
}

// ---------------- prep x: one pass -> x_hi, x_lo, xT(bf16 [IN][B]) ----------------
__global__ __launch_bounds__(256) void k_prep_x(const float* __restrict__ x,
                                                unsigned short* __restrict__ hi,
                                                unsigned short* __restrict__ lo,
                                                unsigned short* __restrict__ xT) {
    __shared__ unsigned short tile[64][65];
    const int b0 = blockIdx.y * 64, i0 = blockIdx.x * 64;
#pragma unroll
    for (int it = 0; it < 16; ++it) {
        int idx = it * 256 + threadIdx.x;
        int r = idx >> 6, c = idx & 63;
        float v = x[(size_t)(b0 + r) * 4096 + i0 + c];
        unsigned short h = f2bf(v);
        unsigned short l = f2bf(v - bf2f(h));
        hi[(size_t)(b0 + r) * 4096 + i0 + c] = h;
        lo[(size_t)(b0 + r) * 4096 + i0 + c] = l;
        tile[r][c] = h;
    }
    __syncthreads();
#pragma unroll
    for (int it = 0; it < 16; ++it) {
        int idx = it * 256 + threadIdx.x;
        int r = idx >> 6, c = idx & 63;   // r: i-offset, c: b-offset
        xT[(size_t)(i0 + r) * 8192 + b0 + c] = tile[c][r];
    }
}

// ---------------- GEMM1: C[b][o] = sum_k x[b][k]*w[o][k], bf16x3 ----------------
// Tile 256(M)x128(N), BK=32, ring-3. Slot: Ah[0,8192) Al[8192,16384)
// Bh[16384,20480) Bl[20480,24576) ushorts (48 KB).
__global__ __launch_bounds__(512, 2) void k_gemm1(const unsigned short* __restrict__ Ah,
                                                  const unsigned short* __restrict__ Al,
                                                  const unsigned short* __restrict__ Bh,
                                                  const unsigned short* __restrict__ Bl,
                                                  float* __restrict__ C,
                                                  float* __restrict__ acc_act) {
    __shared__ unsigned short sm[3 * 24576];   // 144 KiB
    const int t = threadIdx.x, lane = t & 63, ln15 = lane & 15, l16 = lane >> 4;
    const int wid = t >> 6, wm = wid >> 2, wn = wid & 3;
    const int nwg = gridDim.x, bid = blockIdx.x;
    const int wg  = (bid & 7) * (nwg >> 3) + (bid >> 3);        // XCD swizzle (nwg%8==0)
    const int bm = wg >> 5, bn = wg & 31;                        // 32 x 32 blocks
    const int arow0 = bm * 256, brow0 = bn * 128;

    // staging: 6 gload_lds(16B)/thread/tile; LDS linear, source pre-swizzled.
    // chunk permutation within 64B row: chk = (cc&3) ^ ((row>>1)&3)  [period-8 banks]
    const unsigned short* gsrc[6];
    int ldso[6];
#pragma unroll
    for (int j = 0; j < 6; ++j) {
        const int c = j * 512 + t;
        if (c < 1024)      { int cc = c;        int row = cc >> 2, chk = (cc & 3) ^ ((row >> 1) & 3); gsrc[j] = Ah + (size_t)(arow0 + row) * 4096 + chk * 8; ldso[j] = cc * 8; }
        else if (c < 2048) { int cc = c - 1024; int row = cc >> 2, chk = (cc & 3) ^ ((row >> 1) & 3); gsrc[j] = Al + (size_t)(arow0 + row) * 4096 + chk * 8; ldso[j] = 8192 + cc * 8; }
        else if (c < 2560) { int cc = c - 2048; int row = cc >> 2, chk = (cc & 3) ^ ((row >> 1) & 3); gsrc[j] = Bh + (size_t)(brow0 + row) * 4096 + chk * 8; ldso[j] = 16384 + cc * 8; }
        else               { int cc = c - 2560; int row = cc >> 2, chk = (cc & 3) ^ ((row >> 1) & 3); gsrc[j] = Bl + (size_t)(brow0 + row) * 4096 + chk * 8; ldso[j] = 20480 + cc * 8; }
    }

    // fragment LDS offsets (read-side swizzle = staging swizzle)
    int aoh[8], aol[8], boh[2], bol[2];
#pragma unroll
    for (int mi = 0; mi < 8; ++mi) {
        const int r = wm * 128 + mi * 16 + ln15;
        const int sw = (l16 ^ ((r >> 1) & 3)) * 8;
        aoh[mi] = r * 32 + sw; aol[mi] = 8192 + r * 32 + sw;
    }
#pragma unroll
    for (int ni = 0; ni < 2; ++ni) {
        const int r = wn * 32 + ni * 16 + ln15;
        const int sw = (l16 ^ ((r >> 1) & 3)) * 8;
        boh[ni] = 16384 + r * 32 + sw; bol[ni] = 20480 + r * 32 + sw;
    }

    f32x4 acc[8][2];
#pragma unroll
    for (int mi = 0; mi < 8; ++mi)
#pragma unroll
        for (int ni = 0; ni < 2; ++ni) acc[mi][ni] = (f32x4){0.f, 0.f, 0.f, 0.f};

    // prologue: stage tiles 0,1 into slots 0,1 (12 loads in flight)
#pragma unroll
    for (int j = 0; j < 6; ++j) gload16(gsrc[j], sm + ldso[j]);
#pragma unroll
    for (int j = 0; j < 6; ++j) gload16(gsrc[j] + 32, sm + 24576 + ldso[j]);

    int scur = 0, snxt = 2;
    for (int kt = 0; kt < 128; ++kt) {
        asm volatile("s_waitcnt vmcnt(6)" ::: "memory");   // tile kt's 6 loads landed
        __builtin_amdgcn_s_barrier();                      // all waves' loads in; kt-1 reads done
        asm volatile("" ::: "memory");
        const unsigned short* rb = sm + scur * 24576;
        bf16x8 vah[8], val[8], vbh[2], vbl[2];
#pragma unroll
        for (int mi = 0; mi < 8; ++mi) { vah[mi] = *(const bf16x8*)(rb + aoh[mi]); val[mi] = *(const bf16x8*)(rb + aol[mi]); }
#pragma unroll
        for (int ni = 0; ni < 2; ++ni) { vbh[ni] = *(const bf16x8*)(rb + boh[ni]); vbl[ni] = *(const bf16x8*)(rb + bol[ni]); }
        { // stage tile kt+2 into slot snxt (= slot of kt-1, freed by barrier above)
            const size_t ko = (size_t)((kt + 2 < 128) ? kt + 2 : 127) * 32;
            unsigned short* sb = sm + snxt * 24576;
#pragma unroll
            for (int j = 0; j < 6; ++j) gload16(gsrc[j] + ko, sb + ldso[j]);
        }
        __builtin_amdgcn_s_setprio(1);
#pragma unroll
        for (int mi = 0; mi < 8; ++mi)
#pragma unroll
            for (int ni = 0; ni < 2; ++ni) {
                acc[mi][ni] = __builtin_amdgcn_mfma_f32_16x16x32_bf16(vah[mi], vbh[ni], acc[mi][ni], 0, 0, 0);
                acc[mi][ni] = __builtin_amdgcn_mfma_f32_16x16x32_bf16(vah[mi], vbl[ni], acc[mi][ni], 0, 0, 0);
                acc[mi][ni] = __builtin_amdgcn_mfma_f32_16x16x32_bf16(val[mi], vbh[ni], acc[mi][ni], 0, 0, 0);
            }
        __builtin_amdgcn_s_setprio(0);
        scur = (scur == 2) ? 0 : scur + 1;
        snxt = (snxt == 2) ? 0 : snxt + 1;
    }
    asm volatile("s_waitcnt vmcnt(0)" ::: "memory");       // drain before LDS dealloc

    // epilogue: C write + fused column-sum (activity)
    const int row0 = bm * 256 + wm * 128, col0 = bn * 128 + wn * 32;
    float cs0 = 0.f, cs1 = 0.f;
#pragma unroll
    for (int mi = 0; mi < 8; ++mi)
#pragma unroll
        for (int j = 0; j < 4; ++j) {
            const int row = row0 + mi * 16 + l16 * 4 + j;
            C[(size_t)row * 4096 + col0 + ln15]      = acc[mi][0][j];
            C[(size_t)row * 4096 + col0 + 16 + ln15] = acc[mi][1][j];
            cs0 += acc[mi][0][j]; cs1 += acc[mi][1][j];
        }
    cs0 += __shfl_xor(cs0, 16, 64); cs0 += __shfl_xor(cs0, 32, 64);
    cs1 += __shfl_xor(cs1, 16, 64); cs1 += __shfl_xor(cs1, 32, 64);
    if (l16 == 0) {
        atomicAdd(&acc_act[col0 + ln15], cs0);
        atomicAdd(&acc_act[col0 + 16 + ln15], cs1);
    }
}

// ---------------- GEMM2: Wout[o][i] = Wf[o][i] + scale * sum_b postT[o][b]*xT[i][b] ----------------
// Tile 256(M)x128(N), BK=64, ring-3. Slot: A[0,16384) B[16384,24576) ushorts.
__global__ __launch_bounds__(512, 2) void k_gemm2(const unsigned short* __restrict__ A,
                                                  const unsigned short* __restrict__ Bx,
                                                  const float* __restrict__ Wf,
                                                  float* __restrict__ Wout, float scale) {
    __shared__ unsigned short sm[3 * 24576];   // 144 KiB
    const int t = threadIdx.x, lane = t & 63, ln15 = lane & 15, l16 = lane >> 4;
    const int wid = t >> 6, wm = wid >> 2, wn = wid & 3;
    const int nwg = gridDim.x, bid = blockIdx.x;
    const int wg  = (bid & 7) * (nwg >> 3) + (bid >> 3);
    const int bm = wg >> 5, bn = wg & 31;                       // 16 x 32 blocks
    const int arow0 = bm * 256, brow0 = bn * 128;

    const unsigned short* gsrc[6];
    int ldso[6];
#pragma unroll
    for (int j = 0; j < 6; ++j) {
        const int c = j * 512 + t;
        if (c < 2048) { int row = c >> 3, chk = (c & 7) ^ (row & 7); gsrc[j] = A + (size_t)(arow0 + row) * 8192 + chk * 8; ldso[j] = c * 8; }
        else { int cc = c - 2048; int row = cc >> 3, chk = (cc & 7) ^ (row & 7); gsrc[j] = Bx + (size_t)(brow0 + row) * 8192 + chk * 8; ldso[j] = 16384 + cc * 8; }
    }

    int ao0[8], ao1[8], bo0[2], bo1[2];
#pragma unroll
    for (int mi = 0; mi < 8; ++mi) {
        const int r = wm * 128 + mi * 16 + ln15;
        ao0[mi] = r * 64 + ((l16 ^ (r & 7)) * 8);
        ao1[mi] = r * 64 + (((4 + l16) ^ (r & 7)) * 8);
    }
#pragma unroll
    for (int ni = 0; ni < 2; ++ni) {
        const int r = wn * 32 + ni * 16 + ln15;
        bo0[ni] = 16384 + r * 64 + ((l16 ^ (r & 7)) * 8);
        bo1[ni] = 16384 + r * 64 + (((4 + l16) ^ (r & 7)) * 8);
    }

    f32x4 acc[8][2];
#pragma unroll
    for (int mi = 0; mi < 8; ++mi)
#pragma unroll
        for (int ni = 0; ni < 2; ++ni) acc[mi][ni] = (f32x4){0.f, 0.f, 0.f, 0.f};

#pragma unroll
    for (int j = 0; j < 6; ++j) gload16(gsrc[j], sm + ldso[j]);
#pragma unroll
    for (int j = 0; j < 6; ++j) gload16(gsrc[j] + 64, sm + 24576 + ldso[j]);

    int scur = 0, snxt = 2;
    for (int kt = 0; kt < 128; ++kt) {
        asm volatile("s_waitcnt vmcnt(6)" ::: "memory");
        __builtin_amdgcn_s_barrier();
        asm volatile("" ::: "memory");
        const unsigned short* rb = sm + scur * 24576;
        bf16x8 va[8], vb[2];
#pragma unroll
        for (int mi = 0; mi < 8; ++mi) va[mi] = *(const bf16x8*)(rb + ao0[mi]);
#pragma unroll
        for (int ni = 0; ni < 2; ++ni) vb[ni] = *(const bf16x8*)(rb + bo0[ni]);
        { const size_t ko = (size_t)((kt + 2 < 128) ? kt + 2 : 127) * 64;
          unsigned short* sb = sm + snxt * 24576;
#pragma unroll
          for (int j = 0; j < 6; ++j) gload16(gsrc[j] + ko, sb + ldso[j]);
        }
        __builtin_amdgcn_s_setprio(1);
#pragma unroll
        for (int mi = 0; mi < 8; ++mi)
#pragma unroll
            for (int ni = 0; ni < 2; ++ni)
                acc[mi][ni] = __builtin_amdgcn_mfma_f32_16x16x32_bf16(va[mi], vb[ni], acc[mi][ni], 0, 0, 0);
        __builtin_amdgcn_s_setprio(0);
        // kk = 1
#pragma unroll
        for (int mi = 0; mi < 8; ++mi) va[mi] = *(const bf16x8*)(rb + ao1[mi]);
#pragma unroll
        for (int ni = 0; ni < 2; ++ni) vb[ni] = *(const bf16x8*)(rb + bo1[ni]);
        __builtin_amdgcn_s_setprio(1);
#pragma unroll
        for (int mi = 0; mi < 8; ++mi)
#pragma unroll
            for (int ni = 0; ni < 2; ++ni)
                acc[mi][ni] = __builtin_amdgcn_mfma_f32_16x16x32_bf16(va[mi], vb[ni], acc[mi][ni], 0, 0, 0);
        __builtin_amdgcn_s_setprio(0);
        scur = (scur == 2) ? 0 : scur + 1;
        snxt = (snxt == 2) ? 0 : snxt + 1;
    }
    asm volatile("s_waitcnt vmcnt(0)" ::: "memory");

    const int row0 = bm * 256 + wm * 128, col0 = bn * 128 + wn * 32;
#pragma unroll
    for (int mi = 0; mi < 8; ++mi)
#pragma unroll
        for (int j = 0; j < 4; ++j) {
            const int row = row0 + mi * 16 + l16 * 4 + j;
            const size_t i0 = (size_t)row * 4096 + col0 + ln15;
            const size_t i1 = i0 + 16;
            Wout[i0] = Wf[i0] + scale * acc[mi][0][j];
            Wout[i1] = Wf[i1] + scale * acc[mi][1][j];
        }
}

// ---------------- threshold EMA ----------------
__global__ __launch_bounds__(256) void k_thr(const float* __restrict__ acc,
                                             const float* __restrict__ thr_in,
                                             float* __restrict__ thr_out) {
    const int o = blockIdx.x * 256 + threadIdx.x;
    const float act = acc[o] * (1.0f / 8192.0f);
    const float t0  = thr_in[o];
    thr_out[o] = t0 + (act * act - t0) / 1000.0f;
}

// ---------------- postT: relu(out - thr) transposed to [OUT][B] bf16 ----------------
__global__ __launch_bounds__(256) void k_postT(const float* __restrict__ out,
                                               const float* __restrict__ thr,
                                               unsigned short* __restrict__ postT) {
    __shared__ unsigned short tile[64][65];
    __shared__ float sthr[64];
    const int b0 = blockIdx.y * 64, o0 = blockIdx.x * 64;
    if (threadIdx.x < 64) sthr[threadIdx.x] = thr[o0 + threadIdx.x];
    __syncthreads();
#pragma unroll
    for (int it = 0; it < 16; ++it) {
        int idx = it * 256 + threadIdx.x;
        int r = idx >> 6, c = idx & 63;
        float v = out[(size_t)(b0 + r) * 4096 + o0 + c] - sthr[c];
        tile[r][c] = f2bf(v > 0.f ? v : 0.f);
    }
    __syncthreads();
#pragma unroll
    for (int it = 0; it < 16; ++it) {
        int idx = it * 256 + threadIdx.x;
        int r = idx >> 6, c = idx & 63;
        postT[(size_t)(o0 + r) * 8192 + b0 + c] = tile[c][r];
    }
}

extern "C" void kernel_launch(void* const* d_in, const int* in_sizes, int n_in,
                              void* d_out, int out_size, void* d_ws, size_t ws_size,
                              hipStream_t stream) {
    const float* x   = (const float*)d_in[0];   // [8192][4096]
    const float* w   = (const float*)d_in[1];   // [4096][4096]
    const float* thr = (const float*)d_in[2];   // [4096]
    const int B = 8192, IN = 4096, OUT = 4096;

    float* out_y   = (float*)d_out;                  // [B][OUT]
    float* out_thr = out_y + (size_t)B * OUT;        // [OUT]
    float* out_w   = out_thr + OUT;                  // [OUT][IN]

    char* ws = (char*)d_ws;
    float* acc_act       = (float*)ws;
    unsigned short* x_hi = (unsigned short*)(ws + 65536);
    unsigned short* x_lo = x_hi + (size_t)B * IN;
    unsigned short* w_hi = x_lo + (size_t)B * IN;
    unsigned short* w_lo = w_hi + (size_t)OUT * IN;
    unsigned short* xT   = w_lo + (size_t)OUT * IN;  // [IN][B] bf16, 64 MiB
    unsigned short* postT = x_lo;   // alias, safe after GEMM1
    (void)ws_size;

    hipMemsetAsync(acc_act, 0, OUT * sizeof(float), stream);

    k_prep_x<<<dim3(IN / 64, B / 64), 256, 0, stream>>>(x, x_hi, x_lo, xT);
    k_cvt_split<<<2048, 256, 0, stream>>>(w, w_hi, w_lo, OUT * IN / 4);

    k_gemm1<<<1024, 512, 0, stream>>>(x_hi, x_lo, w_hi, w_lo, out_y, acc_act);

    k_thr<<<OUT / 256, 256, 0, stream>>>(acc_act, thr, out_thr);

    k_postT<<<dim3(OUT / 64, B / 64), 256, 0, stream>>>(out_y, out_thr, postT);

    k_gemm2<<<512, 512, 0, stream>>>(postT, xT, w, out_w, (float)(0.001 / 8192.0));
}

// Round 6
// 1372.517 us; speedup vs baseline: 1.0476x; 1.0020x over previous
//
#include <hip/hip_runtime.h>
#include <hip/hip_bf16.h>

// BCM plasticity: output = x @ W^T ; thr' = thr + (mean_b(output)^2 - thr)/TAU ;
// post = relu(output - thr') ; W' = W + (LR/B) post^T @ x
// B=8192, IN=OUT=4096, fp32.
// GEMM1 bf16x3 (ah*bh + ah*bl + al*bh), GEMM2 plain bf16.
// R4 kernel, 2nd resubmit (R4/R5 benches were infra acquisition timeouts):
// register double-buffer across K-tiles (MFMA consumes prev-tile frags while
// this tile's ds_reads are in flight) + 4Mx2N wave map (64x64 wave tile,
// 16 reads/tile). Ring-3 slots, counted vmcnt(6), raw barriers (R2/R3-proven).

typedef __attribute__((ext_vector_type(8))) short   bf16x8;
typedef __attribute__((ext_vector_type(4))) float   f32x4;

#define ASG __attribute__((address_space(1)))
#define ASL __attribute__((address_space(3)))

__device__ __forceinline__ void gload16(const void* g, void* l) {
    __builtin_amdgcn_global_load_lds((const ASG void*)g, (ASL void*)l, 16, 0, 0);
}

__device__ __forceinline__ unsigned short f2bf(float x) {
    union { float f; unsigned u; } v; v.f = x;
    unsigned r = v.u;
    r += 0x7fffu + ((r >> 16) & 1u);
    return (unsigned short)(r >> 16);
}
__device__ __forceinline__ float bf2f(unsigned short u) {
    union { unsigned u; float f; } v; v.u = ((unsigned)u) << 16;
    return v.f;
}

// ---------------- conversion: f32 -> (hi, lo) bf16 (used for W) ----------------
__global__ __launch_bounds__(256) void k_cvt_split(const float* __restrict__ src,
                                                   unsigned short* __restrict__ hi,
                                                   unsigned short* __restrict__ lo,
                                                   int n4) {
    int i = blockIdx.x * blockDim.x + threadIdx.x;
    int stride = gridDim.x * blockDim.x;
    for (; i < n4; i += stride) {
        float4 v = reinterpret_cast<const float4*>(src)[i];
        ushort4 h, l;
        h.x = f2bf(v.x); l.x = f2bf(v.x - bf2f(h.x));
        h.y = f2bf(v.y); l.y = f2bf(v.y - bf2f(h.y));
        h.z = f2bf(v.z); l.z = f2bf(v.z - bf2f(h.z));
        h.w = f2bf(v.w); l.w = f2bf(v.w - bf2f(h.w));
        reinterpret_cast<ushort4*>(hi)[i] = h;
        reinterpret_cast<ushort4*>(lo)[i] = l;
    }
}

// ---------------- prep x: one pass -> x_hi, x_lo, xT(bf16 [IN][B]) ----------------
__global__ __launch_bounds__(256) void k_prep_x(const float* __restrict__ x,
                                                unsigned short* __restrict__ hi,
                                                unsigned short* __restrict__ lo,
                                                unsigned short* __restrict__ xT) {
    __shared__ unsigned short tile[64][65];
    const int b0 = blockIdx.y * 64, i0 = blockIdx.x * 64;
#pragma unroll
    for (int it = 0; it < 16; ++it) {
        int idx = it * 256 + threadIdx.x;
        int r = idx >> 6, c = idx & 63;
        float v = x[(size_t)(b0 + r) * 4096 + i0 + c];
        unsigned short h = f2bf(v);
        unsigned short l = f2bf(v - bf2f(h));
        hi[(size_t)(b0 + r) * 4096 + i0 + c] = h;
        lo[(size_t)(b0 + r) * 4096 + i0 + c] = l;
        tile[r][c] = h;
    }
    __syncthreads();
#pragma unroll
    for (int it = 0; it < 16; ++it) {
        int idx = it * 256 + threadIdx.x;
        int r = idx >> 6, c = idx & 63;   // r: i-offset, c: b-offset
        xT[(size_t)(i0 + r) * 8192 + b0 + c] = tile[c][r];
    }
}

// ======================= GEMM1 =======================
// Tile 256(M)x128(N), BK=32, ring-3. Slot: Ah[0,8192) Al[8192,16384)
// Bh[16384,20480) Bl[20480,24576) ushorts (48 KB). Waves 4M x 2N, wave tile 64x64.

__device__ __forceinline__ void g1_stage(const unsigned short* const (&gsrc)[6],
                                         const int (&ldso)[6],
                                         unsigned short* sb, int ko) {
#pragma unroll
    for (int j = 0; j < 6; ++j) gload16(gsrc[j] + ko, sb + ldso[j]);
}

__device__ __forceinline__ void g1_read(const unsigned short* rb,
                                        const int (&aoh)[4], const int (&aol)[4],
                                        const int (&boh)[4], const int (&bol)[4],
                                        bf16x8 (&Ah)[4], bf16x8 (&Al)[4],
                                        bf16x8 (&Bh)[4], bf16x8 (&Bl)[4]) {
#pragma unroll
    for (int i = 0; i < 4; ++i) {
        Ah[i] = *(const bf16x8*)(rb + aoh[i]);
        Al[i] = *(const bf16x8*)(rb + aol[i]);
    }
#pragma unroll
    for (int i = 0; i < 4; ++i) {
        Bh[i] = *(const bf16x8*)(rb + boh[i]);
        Bl[i] = *(const bf16x8*)(rb + bol[i]);
    }
}

__device__ __forceinline__ void g1_mfma(const bf16x8 (&Ah)[4], const bf16x8 (&Al)[4],
                                        const bf16x8 (&Bh)[4], const bf16x8 (&Bl)[4],
                                        f32x4 (&acc)[4][4]) {
    __builtin_amdgcn_s_setprio(1);
#pragma unroll
    for (int mi = 0; mi < 4; ++mi)
#pragma unroll
        for (int ni = 0; ni < 4; ++ni) {
            acc[mi][ni] = __builtin_amdgcn_mfma_f32_16x16x32_bf16(Ah[mi], Bh[ni], acc[mi][ni], 0, 0, 0);
            acc[mi][ni] = __builtin_amdgcn_mfma_f32_16x16x32_bf16(Ah[mi], Bl[ni], acc[mi][ni], 0, 0, 0);
            acc[mi][ni] = __builtin_amdgcn_mfma_f32_16x16x32_bf16(Al[mi], Bh[ni], acc[mi][ni], 0, 0, 0);
        }
    __builtin_amdgcn_s_setprio(0);
}

__global__ __launch_bounds__(512, 2) void k_gemm1(const unsigned short* __restrict__ Ah,
                                                  const unsigned short* __restrict__ Al,
                                                  const unsigned short* __restrict__ Bh,
                                                  const unsigned short* __restrict__ Bl,
                                                  float* __restrict__ C,
                                                  float* __restrict__ acc_act) {
    __shared__ unsigned short sm[3 * 24576];   // 144 KiB
    const int t = threadIdx.x, lane = t & 63, ln15 = lane & 15, l16 = lane >> 4;
    const int wid = t >> 6, wm = wid >> 1, wn = wid & 1;
    const int nwg = gridDim.x, bid = blockIdx.x;
    const int wg  = (bid & 7) * (nwg >> 3) + (bid >> 3);        // XCD swizzle (nwg%8==0)
    const int bm = wg >> 5, bn = wg & 31;                        // 32 x 32 blocks
    const int arow0 = bm * 256, brow0 = bn * 128;

    // staging: 6 gload_lds(16B)/thread/tile; LDS linear, source pre-swizzled.
    // chunk permutation within 64B row: chk = (cc&3) ^ ((row>>1)&3)  [period-8 banks]
    const unsigned short* gsrc[6];
    int ldso[6];
#pragma unroll
    for (int j = 0; j < 6; ++j) {
        const int c = j * 512 + t;
        if (c < 1024)      { int cc = c;        int row = cc >> 2, chk = (cc & 3) ^ ((row >> 1) & 3); gsrc[j] = Ah + (size_t)(arow0 + row) * 4096 + chk * 8; ldso[j] = cc * 8; }
        else if (c < 2048) { int cc = c - 1024; int row = cc >> 2, chk = (cc & 3) ^ ((row >> 1) & 3); gsrc[j] = Al + (size_t)(arow0 + row) * 4096 + chk * 8; ldso[j] = 8192 + cc * 8; }
        else if (c < 2560) { int cc = c - 2048; int row = cc >> 2, chk = (cc & 3) ^ ((row >> 1) & 3); gsrc[j] = Bh + (size_t)(brow0 + row) * 4096 + chk * 8; ldso[j] = 16384 + cc * 8; }
        else               { int cc = c - 2560; int row = cc >> 2, chk = (cc & 3) ^ ((row >> 1) & 3); gsrc[j] = Bl + (size_t)(brow0 + row) * 4096 + chk * 8; ldso[j] = 20480 + cc * 8; }
    }

    // fragment LDS offsets (read-side swizzle = staging swizzle)
    int aoh[4], aol[4], boh[4], bol[4];
#pragma unroll
    for (int mi = 0; mi < 4; ++mi) {
        const int r = wm * 64 + mi * 16 + ln15;
        const int sw = (l16 ^ ((r >> 1) & 3)) * 8;
        aoh[mi] = r * 32 + sw; aol[mi] = 8192 + r * 32 + sw;
    }
#pragma unroll
    for (int ni = 0; ni < 4; ++ni) {
        const int r = wn * 64 + ni * 16 + ln15;
        const int sw = (l16 ^ ((r >> 1) & 3)) * 8;
        boh[ni] = 16384 + r * 32 + sw; bol[ni] = 20480 + r * 32 + sw;
    }

    f32x4 acc[4][4];
#pragma unroll
    for (int i = 0; i < 4; ++i)
#pragma unroll
        for (int j = 0; j < 4; ++j) acc[i][j] = (f32x4){0.f, 0.f, 0.f, 0.f};

    bf16x8 A0h[4], A0l[4], B0h[4], B0l[4];
    bf16x8 A1h[4], A1l[4], B1h[4], B1l[4];

    // prologue: stage tiles 0,1,2 into slots 0,1,2 (18 loads in flight)
    g1_stage(gsrc, ldso, sm, 0);
    g1_stage(gsrc, ldso, sm + 24576, 32);
    g1_stage(gsrc, ldso, sm + 2 * 24576, 64);
    asm volatile("s_waitcnt vmcnt(12)" ::: "memory");   // tile 0 landed
    __builtin_amdgcn_s_barrier();
    g1_read(sm, aoh, aol, boh, bol, A0h, A0l, B0h, B0l);
    asm volatile("s_waitcnt lgkmcnt(0)" ::: "memory");
    __builtin_amdgcn_sched_barrier(0);

    int sRead = 1, sStage = 0;     // next read: tile1@slot1; next stage: tile3@slot0
#pragma unroll 1
    for (int i = 0; i < 64; ++i) {
        // ---- phase 0: compute kt=2i (set0), read kt+1 (set1), stage kt+3 ----
        asm volatile("s_waitcnt vmcnt(6)" ::: "memory");   // tile kt+1 landed
        __builtin_amdgcn_s_barrier();
        g1_read(sm + sRead * 24576, aoh, aol, boh, bol, A1h, A1l, B1h, B1l);
        { int kst = 2 * i + 3; if (kst > 127) kst = 127;
          g1_stage(gsrc, ldso, sm + sStage * 24576, kst * 32); }
        g1_mfma(A0h, A0l, B0h, B0l, acc);
        asm volatile("s_waitcnt lgkmcnt(0)" ::: "memory");
        __builtin_amdgcn_sched_barrier(0);
        sRead = (sRead == 2) ? 0 : sRead + 1;
        sStage = (sStage == 2) ? 0 : sStage + 1;
        // ---- phase 1: compute kt=2i+1 (set1), read kt+2 (set0), stage kt+4 ----
        asm volatile("s_waitcnt vmcnt(6)" ::: "memory");
        __builtin_amdgcn_s_barrier();
        g1_read(sm + sRead * 24576, aoh, aol, boh, bol, A0h, A0l, B0h, B0l);
        { int kst = 2 * i + 4; if (kst > 127) kst = 127;
          g1_stage(gsrc, ldso, sm + sStage * 24576, kst * 32); }
        g1_mfma(A1h, A1l, B1h, B1l, acc);
        asm volatile("s_waitcnt lgkmcnt(0)" ::: "memory");
        __builtin_amdgcn_sched_barrier(0);
        sRead = (sRead == 2) ? 0 : sRead + 1;
        sStage = (sStage == 2) ? 0 : sStage + 1;
    }
    asm volatile("s_waitcnt vmcnt(0)" ::: "memory");       // drain before exit

    // epilogue: C write + fused column-sum (activity)
    const int row0 = bm * 256 + wm * 64, col0 = bn * 128 + wn * 64;
    float cs[4] = {0.f, 0.f, 0.f, 0.f};
#pragma unroll
    for (int mi = 0; mi < 4; ++mi)
#pragma unroll
        for (int ni = 0; ni < 4; ++ni)
#pragma unroll
            for (int j = 0; j < 4; ++j) {
                const int row = row0 + mi * 16 + l16 * 4 + j;
                C[(size_t)row * 4096 + col0 + ni * 16 + ln15] = acc[mi][ni][j];
                cs[ni] += acc[mi][ni][j];
            }
#pragma unroll
    for (int ni = 0; ni < 4; ++ni) {
        cs[ni] += __shfl_xor(cs[ni], 16, 64);
        cs[ni] += __shfl_xor(cs[ni], 32, 64);
    }
    if (l16 == 0) {
#pragma unroll
        for (int ni = 0; ni < 4; ++ni)
            atomicAdd(&acc_act[col0 + ni * 16 + ln15], cs[ni]);
    }
}

// ======================= GEMM2 =======================
// Wout[o][i] = Wf[o][i] + scale * sum_b postT[o][b]*xT[i][b]
// Tile 256(M)x128(N), BK=64, ring-3. Slot: A[0,16384) B[16384,24576) ushorts.
// Waves 4M x 2N, wave tile 64x64.

__device__ __forceinline__ void g2_stage(const unsigned short* const (&gsrc)[6],
                                         const int (&ldso)[6],
                                         unsigned short* sb, int ko) {
#pragma unroll
    for (int j = 0; j < 6; ++j) gload16(gsrc[j] + ko, sb + ldso[j]);
}

__device__ __forceinline__ void g2_read(const unsigned short* rb,
                                        const int (&ao0)[4], const int (&ao1)[4],
                                        const int (&bo0)[4], const int (&bo1)[4],
                                        bf16x8 (&A0)[4], bf16x8 (&A1)[4],
                                        bf16x8 (&B0)[4], bf16x8 (&B1)[4]) {
#pragma unroll
    for (int i = 0; i < 4; ++i) {
        A0[i] = *(const bf16x8*)(rb + ao0[i]);
        A1[i] = *(const bf16x8*)(rb + ao1[i]);
    }
#pragma unroll
    for (int i = 0; i < 4; ++i) {
        B0[i] = *(const bf16x8*)(rb + bo0[i]);
        B1[i] = *(const bf16x8*)(rb + bo1[i]);
    }
}

__device__ __forceinline__ void g2_mfma(const bf16x8 (&A0)[4], const bf16x8 (&A1)[4],
                                        const bf16x8 (&B0)[4], const bf16x8 (&B1)[4],
                                        f32x4 (&acc)[4][4]) {
    __builtin_amdgcn_s_setprio(1);
#pragma unroll
    for (int mi = 0; mi < 4; ++mi)
#pragma unroll
        for (int ni = 0; ni < 4; ++ni)
            acc[mi][ni] = __builtin_amdgcn_mfma_f32_16x16x32_bf16(A0[mi], B0[ni], acc[mi][ni], 0, 0, 0);
#pragma unroll
    for (int mi = 0; mi < 4; ++mi)
#pragma unroll
        for (int ni = 0; ni < 4; ++ni)
            acc[mi][ni] = __builtin_amdgcn_mfma_f32_16x16x32_bf16(A1[mi], B1[ni], acc[mi][ni], 0, 0, 0);
    __builtin_amdgcn_s_setprio(0);
}

__global__ __launch_bounds__(512, 2) void k_gemm2(const unsigned short* __restrict__ A,
                                                  const unsigned short* __restrict__ Bx,
                                                  const float* __restrict__ Wf,
                                                  float* __restrict__ Wout, float scale) {
    __shared__ unsigned short sm[3 * 24576];   // 144 KiB
    const int t = threadIdx.x, lane = t & 63, ln15 = lane & 15, l16 = lane >> 4;
    const int wid = t >> 6, wm = wid >> 1, wn = wid & 1;
    const int nwg = gridDim.x, bid = blockIdx.x;
    const int wg  = (bid & 7) * (nwg >> 3) + (bid >> 3);
    const int bm = wg >> 5, bn = wg & 31;                       // 16 x 32 blocks
    const int arow0 = bm * 256, brow0 = bn * 128;

    const unsigned short* gsrc[6];
    int ldso[6];
#pragma unroll
    for (int j = 0; j < 6; ++j) {
        const int c = j * 512 + t;
        if (c < 2048) { int row = c >> 3, chk = (c & 7) ^ (row & 7); gsrc[j] = A + (size_t)(arow0 + row) * 8192 + chk * 8; ldso[j] = c * 8; }
        else { int cc = c - 2048; int row = cc >> 3, chk = (cc & 7) ^ (row & 7); gsrc[j] = Bx + (size_t)(brow0 + row) * 8192 + chk * 8; ldso[j] = 16384 + cc * 8; }
    }

    int ao0[4], ao1[4], bo0[4], bo1[4];
#pragma unroll
    for (int mi = 0; mi < 4; ++mi) {
        const int r = wm * 64 + mi * 16 + ln15;
        ao0[mi] = r * 64 + ((l16 ^ (r & 7)) * 8);
        ao1[mi] = r * 64 + (((4 + l16) ^ (r & 7)) * 8);
    }
#pragma unroll
    for (int ni = 0; ni < 4; ++ni) {
        const int r = wn * 64 + ni * 16 + ln15;
        bo0[ni] = 16384 + r * 64 + ((l16 ^ (r & 7)) * 8);
        bo1[ni] = 16384 + r * 64 + (((4 + l16) ^ (r & 7)) * 8);
    }

    f32x4 acc[4][4];
#pragma unroll
    for (int i = 0; i < 4; ++i)
#pragma unroll
        for (int j = 0; j < 4; ++j) acc[i][j] = (f32x4){0.f, 0.f, 0.f, 0.f};

    bf16x8 A0k0[4], A0k1[4], B0k0[4], B0k1[4];
    bf16x8 A1k0[4], A1k1[4], B1k0[4], B1k1[4];

    g2_stage(gsrc, ldso, sm, 0);
    g2_stage(gsrc, ldso, sm + 24576, 64);
    g2_stage(gsrc, ldso, sm + 2 * 24576, 128);
    asm volatile("s_waitcnt vmcnt(12)" ::: "memory");
    __builtin_amdgcn_s_barrier();
    g2_read(sm, ao0, ao1, bo0, bo1, A0k0, A0k1, B0k0, B0k1);
    asm volatile("s_waitcnt lgkmcnt(0)" ::: "memory");
    __builtin_amdgcn_sched_barrier(0);

    int sRead = 1, sStage = 0;
#pragma unroll 1
    for (int i = 0; i < 64; ++i) {
        asm volatile("s_waitcnt vmcnt(6)" ::: "memory");
        __builtin_amdgcn_s_barrier();
        g2_read(sm + sRead * 24576, ao0, ao1, bo0, bo1, A1k0, A1k1, B1k0, B1k1);
        { int kst = 2 * i + 3; if (kst > 127) kst = 127;
          g2_stage(gsrc, ldso, sm + sStage * 24576, kst * 64); }
        g2_mfma(A0k0, A0k1, B0k0, B0k1, acc);
        asm volatile("s_waitcnt lgkmcnt(0)" ::: "memory");
        __builtin_amdgcn_sched_barrier(0);
        sRead = (sRead == 2) ? 0 : sRead + 1;
        sStage = (sStage == 2) ? 0 : sStage + 1;

        asm volatile("s_waitcnt vmcnt(6)" ::: "memory");
        __builtin_amdgcn_s_barrier();
        g2_read(sm + sRead * 24576, ao0, ao1, bo0, bo1, A0k0, A0k1, B0k0, B0k1);
        { int kst = 2 * i + 4; if (kst > 127) kst = 127;
          g2_stage(gsrc, ldso, sm + sStage * 24576, kst * 64); }
        g2_mfma(A1k0, A1k1, B1k0, B1k1, acc);
        asm volatile("s_waitcnt lgkmcnt(0)" ::: "memory");
        __builtin_amdgcn_sched_barrier(0);
        sRead = (sRead == 2) ? 0 : sRead + 1;
        sStage = (sStage == 2) ? 0 : sStage + 1;
    }
    asm volatile("s_waitcnt vmcnt(0)" ::: "memory");

    const int row0 = bm * 256 + wm * 64, col0 = bn * 128 + wn * 64;
#pragma unroll
    for (int mi = 0; mi < 4; ++mi)
#pragma unroll
        for (int ni = 0; ni < 4; ++ni)
#pragma unroll
            for (int j = 0; j < 4; ++j) {
                const int row = row0 + mi * 16 + l16 * 4 + j;
                const size_t idx = (size_t)row * 4096 + col0 + ni * 16 + ln15;
                Wout[idx] = Wf[idx] + scale * acc[mi][ni][j];
            }
}

// ---------------- threshold EMA ----------------
__global__ __launch_bounds__(256) void k_thr(const float* __restrict__ acc,
                                             const float* __restrict__ thr_in,
                                             float* __restrict__ thr_out) {
    const int o = blockIdx.x * 256 + threadIdx.x;
    const float act = acc[o] * (1.0f / 8192.0f);
    const float t0  = thr_in[o];
    thr_out[o] = t0 + (act * act - t0) / 1000.0f;
}

// ---------------- postT: relu(out - thr) transposed to [OUT][B] bf16 ----------------
__global__ __launch_bounds__(256) void k_postT(const float* __restrict__ out,
                                               const float* __restrict__ thr,
                                               unsigned short* __restrict__ postT) {
    __shared__ unsigned short tile[64][65];
    __shared__ float sthr[64];
    const int b0 = blockIdx.y * 64, o0 = blockIdx.x * 64;
    if (threadIdx.x < 64) sthr[threadIdx.x] = thr[o0 + threadIdx.x];
    __syncthreads();
#pragma unroll
    for (int it = 0; it < 16; ++it) {
        int idx = it * 256 + threadIdx.x;
        int r = idx >> 6, c = idx & 63;
        float v = out[(size_t)(b0 + r) * 4096 + o0 + c] - sthr[c];
        tile[r][c] = f2bf(v > 0.f ? v : 0.f);
    }
    __syncthreads();
#pragma unroll
    for (int it = 0; it < 16; ++it) {
        int idx = it * 256 + threadIdx.x;
        int r = idx >> 6, c = idx & 63;
        postT[(size_t)(o0 + r) * 8192 + b0 + c] = tile[c][r];
    }
}

extern "C" void kernel_launch(void* const* d_in, const int* in_sizes, int n_in,
                              void* d_out, int out_size, void* d_ws, size_t ws_size,
                              hipStream_t stream) {
    const float* x   = (const float*)d_in[0];   // [8192][4096]
    const float* w   = (const float*)d_in[1];   // [4096][4096]
    const float* thr = (const float*)d_in[2];   // [4096]
    const int B = 8192, IN = 4096, OUT = 4096;

    float* out_y   = (float*)d_out;                  // [B][OUT]
    float* out_thr = out_y + (size_t)B * OUT;        // [OUT]
    float* out_w   = out_thr + OUT;                  // [OUT][IN]

    char* ws = (char*)d_ws;
    float* acc_act       = (float*)ws;
    unsigned short* x_hi = (unsigned short*)(ws + 65536);
    unsigned short* x_lo = x_hi + (size_t)B * IN;
    unsigned short* w_hi = x_lo + (size_t)B * IN;
    unsigned short* w_lo = w_hi + (size_t)OUT * IN;
    unsigned short* xT   = w_lo + (size_t)OUT * IN;  // [IN][B] bf16, 64 MiB
    unsigned short* postT = x_lo;   // alias, safe after GEMM1
    (void)ws_size;

    hipMemsetAsync(acc_act, 0, OUT * sizeof(float), stream);

    k_prep_x<<<dim3(IN / 64, B / 64), 256, 0, stream>>>(x, x_hi, x_lo, xT);
    k_cvt_split<<<2048, 256, 0, stream>>>(w, w_hi, w_lo, OUT * IN / 4);

    k_gemm1<<<1024, 512, 0, stream>>>(x_hi, x_lo, w_hi, w_lo, out_y, acc_act);

    k_thr<<<OUT / 256, 256, 0, stream>>>(acc_act, thr, out_thr);

    k_postT<<<dim3(OUT / 64, B / 64), 256, 0, stream>>>(out_y, out_thr, postT);

    k_gemm2<<<512, 512, 0, stream>>>(postT, xT, w, out_w, (float)(0.001 / 8192.0));
}

// Round 7
// 1369.158 us; speedup vs baseline: 1.0502x; 1.0025x over previous
//
#include <hip/hip_runtime.h>
#include <hip/hip_bf16.h>

// BCM plasticity: output = x @ W^T ; thr' = thr + (mean_b(output)^2 - thr)/TAU ;
// post = relu(output - thr') ; W' = W + (LR/B) post^T @ x
// B=8192, IN=OUT=4096, fp32.
// GEMM1 bf16x3 (ah*bh + ah*bl + al*bh), GEMM2 plain bf16.
// R7: R6 failed because hipcc reordered the MFMA burst above the fragment
// ds_reads (VGPR_Count=112 proved one live set -> serial phases). Fix: pin
// issue order with sched_barrier(0) BETWEEN [reads+stage] and the MFMA
// cluster so MFMAs execute while ds_reads drain on the LDS pipe.

typedef __attribute__((ext_vector_type(8))) short   bf16x8;
typedef __attribute__((ext_vector_type(4))) float   f32x4;

#define ASG __attribute__((address_space(1)))
#define ASL __attribute__((address_space(3)))

__device__ __forceinline__ void gload16(const void* g, void* l) {
    __builtin_amdgcn_global_load_lds((const ASG void*)g, (ASL void*)l, 16, 0, 0);
}

__device__ __forceinline__ unsigned short f2bf(float x) {
    union { float f; unsigned u; } v; v.f = x;
    unsigned r = v.u;
    r += 0x7fffu + ((r >> 16) & 1u);
    return (unsigned short)(r >> 16);
}
__device__ __forceinline__ float bf2f(unsigned short u) {
    union { unsigned u; float f; } v; v.u = ((unsigned)u) << 16;
    return v.f;
}

// ---------------- conversion: f32 -> (hi, lo) bf16 (used for W) ----------------
__global__ __launch_bounds__(256) void k_cvt_split(const float* __restrict__ src,
                                                   unsigned short* __restrict__ hi,
                                                   unsigned short* __restrict__ lo,
                                                   int n4) {
    int i = blockIdx.x * blockDim.x + threadIdx.x;
    int stride = gridDim.x * blockDim.x;
    for (; i < n4; i += stride) {
        float4 v = reinterpret_cast<const float4*>(src)[i];
        ushort4 h, l;
        h.x = f2bf(v.x); l.x = f2bf(v.x - bf2f(h.x));
        h.y = f2bf(v.y); l.y = f2bf(v.y - bf2f(h.y));
        h.z = f2bf(v.z); l.z = f2bf(v.z - bf2f(h.z));
        h.w = f2bf(v.w); l.w = f2bf(v.w - bf2f(h.w));
        reinterpret_cast<ushort4*>(hi)[i] = h;
        reinterpret_cast<ushort4*>(lo)[i] = l;
    }
}

// ---------------- prep x: one pass -> x_hi, x_lo, xT(bf16 [IN][B]) ----------------
__global__ __launch_bounds__(256) void k_prep_x(const float* __restrict__ x,
                                                unsigned short* __restrict__ hi,
                                                unsigned short* __restrict__ lo,
                                                unsigned short* __restrict__ xT) {
    __shared__ unsigned short tile[64][65];
    const int b0 = blockIdx.y * 64, i0 = blockIdx.x * 64;
#pragma unroll
    for (int it = 0; it < 16; ++it) {
        int idx = it * 256 + threadIdx.x;
        int r = idx >> 6, c = idx & 63;
        float v = x[(size_t)(b0 + r) * 4096 + i0 + c];
        unsigned short h = f2bf(v);
        unsigned short l = f2bf(v - bf2f(h));
        hi[(size_t)(b0 + r) * 4096 + i0 + c] = h;
        lo[(size_t)(b0 + r) * 4096 + i0 + c] = l;
        tile[r][c] = h;
    }
    __syncthreads();
#pragma unroll
    for (int it = 0; it < 16; ++it) {
        int idx = it * 256 + threadIdx.x;
        int r = idx >> 6, c = idx & 63;   // r: i-offset, c: b-offset
        xT[(size_t)(i0 + r) * 8192 + b0 + c] = tile[c][r];
    }
}

// ======================= GEMM1 =======================
// Tile 256(M)x128(N), BK=32, ring-3. Slot: Ah[0,8192) Al[8192,16384)
// Bh[16384,20480) Bl[20480,24576) ushorts (48 KB). Waves 4M x 2N, wave tile 64x64.

__device__ __forceinline__ void g1_stage(const unsigned short* const (&gsrc)[6],
                                         const int (&ldso)[6],
                                         unsigned short* sb, int ko) {
#pragma unroll
    for (int j = 0; j < 6; ++j) gload16(gsrc[j] + ko, sb + ldso[j]);
}

__device__ __forceinline__ void g1_read(const unsigned short* rb,
                                        const int (&aoh)[4], const int (&aol)[4],
                                        const int (&boh)[4], const int (&bol)[4],
                                        bf16x8 (&Ah)[4], bf16x8 (&Al)[4],
                                        bf16x8 (&Bh)[4], bf16x8 (&Bl)[4]) {
#pragma unroll
    for (int i = 0; i < 4; ++i) {
        Ah[i] = *(const bf16x8*)(rb + aoh[i]);
        Al[i] = *(const bf16x8*)(rb + aol[i]);
    }
#pragma unroll
    for (int i = 0; i < 4; ++i) {
        Bh[i] = *(const bf16x8*)(rb + boh[i]);
        Bl[i] = *(const bf16x8*)(rb + bol[i]);
    }
}

__device__ __forceinline__ void g1_mfma(const bf16x8 (&Ah)[4], const bf16x8 (&Al)[4],
                                        const bf16x8 (&Bh)[4], const bf16x8 (&Bl)[4],
                                        f32x4 (&acc)[4][4]) {
    __builtin_amdgcn_s_setprio(1);
#pragma unroll
    for (int mi = 0; mi < 4; ++mi)
#pragma unroll
        for (int ni = 0; ni < 4; ++ni) {
            acc[mi][ni] = __builtin_amdgcn_mfma_f32_16x16x32_bf16(Ah[mi], Bh[ni], acc[mi][ni], 0, 0, 0);
            acc[mi][ni] = __builtin_amdgcn_mfma_f32_16x16x32_bf16(Ah[mi], Bl[ni], acc[mi][ni], 0, 0, 0);
            acc[mi][ni] = __builtin_amdgcn_mfma_f32_16x16x32_bf16(Al[mi], Bh[ni], acc[mi][ni], 0, 0, 0);
        }
    __builtin_amdgcn_s_setprio(0);
}

__global__ __launch_bounds__(512, 2) void k_gemm1(const unsigned short* __restrict__ Ah,
                                                  const unsigned short* __restrict__ Al,
                                                  const unsigned short* __restrict__ Bh,
                                                  const unsigned short* __restrict__ Bl,
                                                  float* __restrict__ C,
                                                  float* __restrict__ acc_act) {
    __shared__ unsigned short sm[3 * 24576];   // 144 KiB
    const int t = threadIdx.x, lane = t & 63, ln15 = lane & 15, l16 = lane >> 4;
    const int wid = t >> 6, wm = wid >> 1, wn = wid & 1;
    const int nwg = gridDim.x, bid = blockIdx.x;
    const int wg  = (bid & 7) * (nwg >> 3) + (bid >> 3);        // XCD swizzle (nwg%8==0)
    const int bm = wg >> 5, bn = wg & 31;                        // 32 x 32 blocks
    const int arow0 = bm * 256, brow0 = bn * 128;

    // staging: 6 gload_lds(16B)/thread/tile; LDS linear, source pre-swizzled.
    // chunk permutation within 64B row: chk = (cc&3) ^ ((row>>1)&3)  [period-8 banks]
    const unsigned short* gsrc[6];
    int ldso[6];
#pragma unroll
    for (int j = 0; j < 6; ++j) {
        const int c = j * 512 + t;
        if (c < 1024)      { int cc = c;        int row = cc >> 2, chk = (cc & 3) ^ ((row >> 1) & 3); gsrc[j] = Ah + (size_t)(arow0 + row) * 4096 + chk * 8; ldso[j] = cc * 8; }
        else if (c < 2048) { int cc = c - 1024; int row = cc >> 2, chk = (cc & 3) ^ ((row >> 1) & 3); gsrc[j] = Al + (size_t)(arow0 + row) * 4096 + chk * 8; ldso[j] = 8192 + cc * 8; }
        else if (c < 2560) { int cc = c - 2048; int row = cc >> 2, chk = (cc & 3) ^ ((row >> 1) & 3); gsrc[j] = Bh + (size_t)(brow0 + row) * 4096 + chk * 8; ldso[j] = 16384 + cc * 8; }
        else               { int cc = c - 2560; int row = cc >> 2, chk = (cc & 3) ^ ((row >> 1) & 3); gsrc[j] = Bl + (size_t)(brow0 + row) * 4096 + chk * 8; ldso[j] = 20480 + cc * 8; }
    }

    // fragment LDS offsets (read-side swizzle = staging swizzle)
    int aoh[4], aol[4], boh[4], bol[4];
#pragma unroll
    for (int mi = 0; mi < 4; ++mi) {
        const int r = wm * 64 + mi * 16 + ln15;
        const int sw = (l16 ^ ((r >> 1) & 3)) * 8;
        aoh[mi] = r * 32 + sw; aol[mi] = 8192 + r * 32 + sw;
    }
#pragma unroll
    for (int ni = 0; ni < 4; ++ni) {
        const int r = wn * 64 + ni * 16 + ln15;
        const int sw = (l16 ^ ((r >> 1) & 3)) * 8;
        boh[ni] = 16384 + r * 32 + sw; bol[ni] = 20480 + r * 32 + sw;
    }

    f32x4 acc[4][4];
#pragma unroll
    for (int i = 0; i < 4; ++i)
#pragma unroll
        for (int j = 0; j < 4; ++j) acc[i][j] = (f32x4){0.f, 0.f, 0.f, 0.f};

    bf16x8 A0h[4], A0l[4], B0h[4], B0l[4];
    bf16x8 A1h[4], A1l[4], B1h[4], B1l[4];

    // prologue: stage tiles 0,1,2 into slots 0,1,2 (18 loads in flight)
    g1_stage(gsrc, ldso, sm, 0);
    g1_stage(gsrc, ldso, sm + 24576, 32);
    g1_stage(gsrc, ldso, sm + 2 * 24576, 64);
    asm volatile("s_waitcnt vmcnt(12)" ::: "memory");   // tile 0 landed
    __builtin_amdgcn_s_barrier();
    g1_read(sm, aoh, aol, boh, bol, A0h, A0l, B0h, B0l);
    asm volatile("s_waitcnt lgkmcnt(0)" ::: "memory");
    __builtin_amdgcn_sched_barrier(0);

    int sRead = 1, sStage = 0;     // next read: tile1@slot1; next stage: tile3@slot0
#pragma unroll 1
    for (int i = 0; i < 64; ++i) {
        // ---- phase 0: read kt+1 (set1) + stage kt+3 issued FIRST, then MFMA kt (set0) ----
        asm volatile("s_waitcnt vmcnt(6)" ::: "memory");   // tile kt+1 landed
        __builtin_amdgcn_s_barrier();
        g1_read(sm + sRead * 24576, aoh, aol, boh, bol, A1h, A1l, B1h, B1l);
        { int kst = 2 * i + 3; if (kst > 127) kst = 127;
          g1_stage(gsrc, ldso, sm + sStage * 24576, kst * 32); }
        __builtin_amdgcn_sched_barrier(0);   // pin: reads+stage issue BEFORE MFMAs
        g1_mfma(A0h, A0l, B0h, B0l, acc);
        asm volatile("s_waitcnt lgkmcnt(0)" ::: "memory");
        __builtin_amdgcn_sched_barrier(0);
        sRead = (sRead == 2) ? 0 : sRead + 1;
        sStage = (sStage == 2) ? 0 : sStage + 1;
        // ---- phase 1: read kt+2 (set0) + stage kt+4, then MFMA kt+1 (set1) ----
        asm volatile("s_waitcnt vmcnt(6)" ::: "memory");
        __builtin_amdgcn_s_barrier();
        g1_read(sm + sRead * 24576, aoh, aol, boh, bol, A0h, A0l, B0h, B0l);
        { int kst = 2 * i + 4; if (kst > 127) kst = 127;
          g1_stage(gsrc, ldso, sm + sStage * 24576, kst * 32); }
        __builtin_amdgcn_sched_barrier(0);
        g1_mfma(A1h, A1l, B1h, B1l, acc);
        asm volatile("s_waitcnt lgkmcnt(0)" ::: "memory");
        __builtin_amdgcn_sched_barrier(0);
        sRead = (sRead == 2) ? 0 : sRead + 1;
        sStage = (sStage == 2) ? 0 : sStage + 1;
    }
    asm volatile("s_waitcnt vmcnt(0)" ::: "memory");       // drain before exit

    // epilogue: C write + fused column-sum (activity)
    const int row0 = bm * 256 + wm * 64, col0 = bn * 128 + wn * 64;
    float cs[4] = {0.f, 0.f, 0.f, 0.f};
#pragma unroll
    for (int mi = 0; mi < 4; ++mi)
#pragma unroll
        for (int ni = 0; ni < 4; ++ni)
#pragma unroll
            for (int j = 0; j < 4; ++j) {
                const int row = row0 + mi * 16 + l16 * 4 + j;
                C[(size_t)row * 4096 + col0 + ni * 16 + ln15] = acc[mi][ni][j];
                cs[ni] += acc[mi][ni][j];
            }
#pragma unroll
    for (int ni = 0; ni < 4; ++ni) {
        cs[ni] += __shfl_xor(cs[ni], 16, 64);
        cs[ni] += __shfl_xor(cs[ni], 32, 64);
    }
    if (l16 == 0) {
#pragma unroll
        for (int ni = 0; ni < 4; ++ni)
            atomicAdd(&acc_act[col0 + ni * 16 + ln15], cs[ni]);
    }
}

// ======================= GEMM2 =======================
// Wout[o][i] = Wf[o][i] + scale * sum_b postT[o][b]*xT[i][b]
// Tile 256(M)x128(N), BK=64, ring-3. Slot: A[0,16384) B[16384,24576) ushorts.
// Waves 4M x 2N, wave tile 64x64.

__device__ __forceinline__ void g2_stage(const unsigned short* const (&gsrc)[6],
                                         const int (&ldso)[6],
                                         unsigned short* sb, int ko) {
#pragma unroll
    for (int j = 0; j < 6; ++j) gload16(gsrc[j] + ko, sb + ldso[j]);
}

__device__ __forceinline__ void g2_read(const unsigned short* rb,
                                        const int (&ao0)[4], const int (&ao1)[4],
                                        const int (&bo0)[4], const int (&bo1)[4],
                                        bf16x8 (&A0)[4], bf16x8 (&A1)[4],
                                        bf16x8 (&B0)[4], bf16x8 (&B1)[4]) {
#pragma unroll
    for (int i = 0; i < 4; ++i) {
        A0[i] = *(const bf16x8*)(rb + ao0[i]);
        A1[i] = *(const bf16x8*)(rb + ao1[i]);
    }
#pragma unroll
    for (int i = 0; i < 4; ++i) {
        B0[i] = *(const bf16x8*)(rb + bo0[i]);
        B1[i] = *(const bf16x8*)(rb + bo1[i]);
    }
}

__device__ __forceinline__ void g2_mfma(const bf16x8 (&A0)[4], const bf16x8 (&A1)[4],
                                        const bf16x8 (&B0)[4], const bf16x8 (&B1)[4],
                                        f32x4 (&acc)[4][4]) {
    __builtin_amdgcn_s_setprio(1);
#pragma unroll
    for (int mi = 0; mi < 4; ++mi)
#pragma unroll
        for (int ni = 0; ni < 4; ++ni)
            acc[mi][ni] = __builtin_amdgcn_mfma_f32_16x16x32_bf16(A0[mi], B0[ni], acc[mi][ni], 0, 0, 0);
#pragma unroll
    for (int mi = 0; mi < 4; ++mi)
#pragma unroll
        for (int ni = 0; ni < 4; ++ni)
            acc[mi][ni] = __builtin_amdgcn_mfma_f32_16x16x32_bf16(A1[mi], B1[ni], acc[mi][ni], 0, 0, 0);
    __builtin_amdgcn_s_setprio(0);
}

__global__ __launch_bounds__(512, 2) void k_gemm2(const unsigned short* __restrict__ A,
                                                  const unsigned short* __restrict__ Bx,
                                                  const float* __restrict__ Wf,
                                                  float* __restrict__ Wout, float scale) {
    __shared__ unsigned short sm[3 * 24576];   // 144 KiB
    const int t = threadIdx.x, lane = t & 63, ln15 = lane & 15, l16 = lane >> 4;
    const int wid = t >> 6, wm = wid >> 1, wn = wid & 1;
    const int nwg = gridDim.x, bid = blockIdx.x;
    const int wg  = (bid & 7) * (nwg >> 3) + (bid >> 3);
    const int bm = wg >> 5, bn = wg & 31;                       // 16 x 32 blocks
    const int arow0 = bm * 256, brow0 = bn * 128;

    const unsigned short* gsrc[6];
    int ldso[6];
#pragma unroll
    for (int j = 0; j < 6; ++j) {
        const int c = j * 512 + t;
        if (c < 2048) { int row = c >> 3, chk = (c & 7) ^ (row & 7); gsrc[j] = A + (size_t)(arow0 + row) * 8192 + chk * 8; ldso[j] = c * 8; }
        else { int cc = c - 2048; int row = cc >> 3, chk = (cc & 7) ^ (row & 7); gsrc[j] = Bx + (size_t)(brow0 + row) * 8192 + chk * 8; ldso[j] = 16384 + cc * 8; }
    }

    int ao0[4], ao1[4], bo0[4], bo1[4];
#pragma unroll
    for (int mi = 0; mi < 4; ++mi) {
        const int r = wm * 64 + mi * 16 + ln15;
        ao0[mi] = r * 64 + ((l16 ^ (r & 7)) * 8);
        ao1[mi] = r * 64 + (((4 + l16) ^ (r & 7)) * 8);
    }
#pragma unroll
    for (int ni = 0; ni < 4; ++ni) {
        const int r = wn * 64 + ni * 16 + ln15;
        bo0[ni] = 16384 + r * 64 + ((l16 ^ (r & 7)) * 8);
        bo1[ni] = 16384 + r * 64 + (((4 + l16) ^ (r & 7)) * 8);
    }

    f32x4 acc[4][4];
#pragma unroll
    for (int i = 0; i < 4; ++i)
#pragma unroll
        for (int j = 0; j < 4; ++j) acc[i][j] = (f32x4){0.f, 0.f, 0.f, 0.f};

    bf16x8 A0k0[4], A0k1[4], B0k0[4], B0k1[4];
    bf16x8 A1k0[4], A1k1[4], B1k0[4], B1k1[4];

    g2_stage(gsrc, ldso, sm, 0);
    g2_stage(gsrc, ldso, sm + 24576, 64);
    g2_stage(gsrc, ldso, sm + 2 * 24576, 128);
    asm volatile("s_waitcnt vmcnt(12)" ::: "memory");
    __builtin_amdgcn_s_barrier();
    g2_read(sm, ao0, ao1, bo0, bo1, A0k0, A0k1, B0k0, B0k1);
    asm volatile("s_waitcnt lgkmcnt(0)" ::: "memory");
    __builtin_amdgcn_sched_barrier(0);

    int sRead = 1, sStage = 0;
#pragma unroll 1
    for (int i = 0; i < 64; ++i) {
        asm volatile("s_waitcnt vmcnt(6)" ::: "memory");
        __builtin_amdgcn_s_barrier();
        g2_read(sm + sRead * 24576, ao0, ao1, bo0, bo1, A1k0, A1k1, B1k0, B1k1);
        { int kst = 2 * i + 3; if (kst > 127) kst = 127;
          g2_stage(gsrc, ldso, sm + sStage * 24576, kst * 64); }
        __builtin_amdgcn_sched_barrier(0);   // pin: reads+stage issue BEFORE MFMAs
        g2_mfma(A0k0, A0k1, B0k0, B0k1, acc);
        asm volatile("s_waitcnt lgkmcnt(0)" ::: "memory");
        __builtin_amdgcn_sched_barrier(0);
        sRead = (sRead == 2) ? 0 : sRead + 1;
        sStage = (sStage == 2) ? 0 : sStage + 1;

        asm volatile("s_waitcnt vmcnt(6)" ::: "memory");
        __builtin_amdgcn_s_barrier();
        g2_read(sm + sRead * 24576, ao0, ao1, bo0, bo1, A0k0, A0k1, B0k0, B0k1);
        { int kst = 2 * i + 4; if (kst > 127) kst = 127;
          g2_stage(gsrc, ldso, sm + sStage * 24576, kst * 64); }
        __builtin_amdgcn_sched_barrier(0);
        g2_mfma(A1k0, A1k1, B1k0, B1k1, acc);
        asm volatile("s_waitcnt lgkmcnt(0)" ::: "memory");
        __builtin_amdgcn_sched_barrier(0);
        sRead = (sRead == 2) ? 0 : sRead + 1;
        sStage = (sStage == 2) ? 0 : sStage + 1;
    }
    asm volatile("s_waitcnt vmcnt(0)" ::: "memory");

    const int row0 = bm * 256 + wm * 64, col0 = bn * 128 + wn * 64;
#pragma unroll
    for (int mi = 0; mi < 4; ++mi)
#pragma unroll
        for (int ni = 0; ni < 4; ++ni)
#pragma unroll
            for (int j = 0; j < 4; ++j) {
                const int row = row0 + mi * 16 + l16 * 4 + j;
                const size_t idx = (size_t)row * 4096 + col0 + ni * 16 + ln15;
                Wout[idx] = Wf[idx] + scale * acc[mi][ni][j];
            }
}

// ---------------- threshold EMA ----------------
__global__ __launch_bounds__(256) void k_thr(const float* __restrict__ acc,
                                             const float* __restrict__ thr_in,
                                             float* __restrict__ thr_out) {
    const int o = blockIdx.x * 256 + threadIdx.x;
    const float act = acc[o] * (1.0f / 8192.0f);
    const float t0  = thr_in[o];
    thr_out[o] = t0 + (act * act - t0) / 1000.0f;
}

// ---------------- postT: relu(out - thr) transposed to [OUT][B] bf16 ----------------
__global__ __launch_bounds__(256) void k_postT(const float* __restrict__ out,
                                               const float* __restrict__ thr,
                                               unsigned short* __restrict__ postT) {
    __shared__ unsigned short tile[64][65];
    __shared__ float sthr[64];
    const int b0 = blockIdx.y * 64, o0 = blockIdx.x * 64;
    if (threadIdx.x < 64) sthr[threadIdx.x] = thr[o0 + threadIdx.x];
    __syncthreads();
#pragma unroll
    for (int it = 0; it < 16; ++it) {
        int idx = it * 256 + threadIdx.x;
        int r = idx >> 6, c = idx & 63;
        float v = out[(size_t)(b0 + r) * 4096 + o0 + c] - sthr[c];
        tile[r][c] = f2bf(v > 0.f ? v : 0.f);
    }
    __syncthreads();
#pragma unroll
    for (int it = 0; it < 16; ++it) {
        int idx = it * 256 + threadIdx.x;
        int r = idx >> 6, c = idx & 63;
        postT[(size_t)(o0 + r) * 8192 + b0 + c] = tile[c][r];
    }
}

extern "C" void kernel_launch(void* const* d_in, const int* in_sizes, int n_in,
                              void* d_out, int out_size, void* d_ws, size_t ws_size,
                              hipStream_t stream) {
    const float* x   = (const float*)d_in[0];   // [8192][4096]
    const float* w   = (const float*)d_in[1];   // [4096][4096]
    const float* thr = (const float*)d_in[2];   // [4096]
    const int B = 8192, IN = 4096, OUT = 4096;

    float* out_y   = (float*)d_out;                  // [B][OUT]
    float* out_thr = out_y + (size_t)B * OUT;        // [OUT]
    float* out_w   = out_thr + OUT;                  // [OUT][IN]

    char* ws = (char*)d_ws;
    float* acc_act       = (float*)ws;
    unsigned short* x_hi = (unsigned short*)(ws + 65536);
    unsigned short* x_lo = x_hi + (size_t)B * IN;
    unsigned short* w_hi = x_lo + (size_t)B * IN;
    unsigned short* w_lo = w_hi + (size_t)OUT * IN;
    unsigned short* xT   = w_lo + (size_t)OUT * IN;  // [IN][B] bf16, 64 MiB
    unsigned short* postT = x_lo;   // alias, safe after GEMM1
    (void)ws_size;

    hipMemsetAsync(acc_act, 0, OUT * sizeof(float), stream);

    k_prep_x<<<dim3(IN / 64, B / 64), 256, 0, stream>>>(x, x_hi, x_lo, xT);
    k_cvt_split<<<2048, 256, 0, stream>>>(w, w_hi, w_lo, OUT * IN / 4);

    k_gemm1<<<1024, 512, 0, stream>>>(x_hi, x_lo, w_hi, w_lo, out_y, acc_act);

    k_thr<<<OUT / 256, 256, 0, stream>>>(acc_act, thr, out_thr);

    k_postT<<<dim3(OUT / 64, B / 64), 256, 0, stream>>>(out_y, out_thr, postT);

    k_gemm2<<<512, 512, 0, stream>>>(postT, xT, w, out_w, (float)(0.001 / 8192.0));
}